// Round 5
// baseline (2813.752 us; speedup 1.0000x reference)
//
#include <hip/hip_runtime.h>

#define DIAGNUM 50000
#define MEDNUM  20000
#define PRONUM  40000
#define FEATDIM 128
#define N1 (DIAGNUM + MEDNUM)   // 70000
#define N2 (PRONUM + MEDNUM)    // 60000
#define NNZ1 1120000
#define NNZ2 960000
#define NNZTOT (2 * NNZ1 + 2 * NNZ2)      // 4160000
#define SLICE 64
#define NB1 ((N1 + SLICE - 1) / SLICE)    // 1094
#define NB2 ((N2 + SLICE - 1) / SLICE)    // 938
#define NBIN (2 * NB1 + 2 * NB2)          // 4064
#define K2_BLOCKS 256
#define K2_CHUNK ((NNZTOT + K2_BLOCKS - 1) / K2_BLOCKS)   // 16250

// bin id for concatenated edge index i
__device__ __forceinline__ int edge_bin(int i, const int* __restrict__ a1r,
                                        const int* __restrict__ a2r) {
    if (i < 2 * NNZ1) {
        int r = a1r[i];
        return ((i < NNZ1) ? 0 : NB1) + (r >> 6);
    } else {
        int j = i - 2 * NNZ1;
        int r = a2r[j];
        return 2 * NB1 + ((j < NNZ2) ? 0 : NB2) + (r >> 6);
    }
}

// ---------------- global bin histogram ----------------
__global__ __launch_bounds__(256) void hist_bins_kernel(const int* __restrict__ a1r,
                                                        const int* __restrict__ a2r,
                                                        int* __restrict__ binCnt) {
    __shared__ int lh[NBIN];
    for (int b = threadIdx.x; b < NBIN; b += 256) lh[b] = 0;
    __syncthreads();
    int stride = gridDim.x * 256;
    for (int i = blockIdx.x * 256 + threadIdx.x; i < NNZTOT; i += stride)
        atomicAdd(&lh[edge_bin(i, a1r, a2r)], 1);
    __syncthreads();
    for (int b = threadIdx.x; b < NBIN; b += 256) {
        int h = lh[b];
        if (h) atomicAdd(&binCnt[b], h);
    }
}

// ---------------- exclusive scan of 4064 bin counts (single block) ----------------
__global__ __launch_bounds__(256) void scan_bins_kernel(const int* __restrict__ binCnt,
                                                        int* __restrict__ binOff,
                                                        int* __restrict__ binCursor) {
    __shared__ int s[256];
    int t = threadIdx.x;
    int vals[16];
    int sum = 0;
#pragma unroll
    for (int k = 0; k < 16; k++) {
        int b = t * 16 + k;
        vals[k] = (b < NBIN) ? binCnt[b] : 0;
        sum += vals[k];
    }
    s[t] = sum;
    __syncthreads();
    for (int off = 1; off < 256; off <<= 1) {
        int y = (t >= off) ? s[t - off] : 0;
        __syncthreads();
        s[t] += y;
        __syncthreads();
    }
    int run = s[t] - sum;   // exclusive prefix of this thread's 16 bins
#pragma unroll
    for (int k = 0; k < 16; k++) {
        int b = t * 16 + k;
        if (b < NBIN) {
            binOff[b] = run;
            binCursor[b] = run;
            run += vals[k];
        }
    }
}

// ---------------- bin scatter (counting sort into 64-row bins) ----------------
// record: .x = (row_in_slice << 17) | col   (row 6b, col 17b), .y = val bits
__global__ __launch_bounds__(256) void binscatter_kernel(
        const int* __restrict__ a1r, const int* __restrict__ a1c,
        const float* __restrict__ a1v,
        const int* __restrict__ a2r, const int* __restrict__ a2c,
        const float* __restrict__ a2v,
        int* __restrict__ binCursor, int2* __restrict__ binned) {
    __shared__ int lh[NBIN];
    for (int b = threadIdx.x; b < NBIN; b += 256) lh[b] = 0;
    __syncthreads();
    int base = blockIdx.x * K2_CHUNK;
    int end  = min(base + K2_CHUNK, NNZTOT);
    // phase 1: block-local histogram (rows only)
    for (int i = base + threadIdx.x; i < end; i += 256)
        atomicAdd(&lh[edge_bin(i, a1r, a2r)], 1);
    __syncthreads();
    // phase 2: reserve per-block spans in each bin
    for (int b = threadIdx.x; b < NBIN; b += 256) {
        int h = lh[b];
        lh[b] = h ? atomicAdd(&binCursor[b], h) : 0;
    }
    __syncthreads();
    // phase 3: write packed records via LDS cursors
    for (int i = base + threadIdx.x; i < end; i += 256) {
        int bin, row, col;
        float val;
        if (i < 2 * NNZ1) {
            row = a1r[i]; col = a1c[i]; val = a1v[i];
            bin = ((i < NNZ1) ? 0 : NB1) + (row >> 6);
        } else {
            int j = i - 2 * NNZ1;
            row = a2r[j]; col = a2c[j]; val = a2v[j];
            bin = 2 * NB1 + ((j < NNZ2) ? 0 : NB2) + (row >> 6);
        }
        int pos = atomicAdd(&lh[bin], 1);
        binned[pos] = make_int2(((row & 63) << 17) | col, __float_as_int(val));
    }
}

// ---------------- fused GCN with LDS accumulators ----------------
// one block per 64-row output slice; two 32 KB fp32 accumulators (adjacency 0/1)
__global__ __launch_bounds__(256) void fused_lds_kernel(
        const int2* __restrict__ binned,
        const int* __restrict__ binOff, const int* __restrict__ binCnt,
        const float* __restrict__ dE, const float* __restrict__ mE,
        const float* __restrict__ pE,
        float* __restrict__ out_d, float* __restrict__ g1med,
        float* __restrict__ out_p, float* __restrict__ g2med) {
    __shared__ float acc[2 * SLICE * FEATDIM];   // 64 KB
    int tid = threadIdx.x;
    float4 z = make_float4(0.f, 0.f, 0.f, 0.f);
    for (int k = tid; k < 2 * SLICE * FEATDIM / 4; k += 256)
        reinterpret_cast<float4*>(acc)[k] = z;
    __syncthreads();

    int blk = blockIdx.x;
    bool isG1 = blk < NB1;
    int slice = isG1 ? blk : blk - NB1;
    int bin0 = isG1 ? slice : 2 * NB1 + slice;
    int bin1 = isG1 ? NB1 + slice : 2 * NB1 + NB2 + slice;
    int nlo  = isG1 ? DIAGNUM : PRONUM;
    const float* xlo = isG1 ? dE : pE;
    const float* xhi = mE;

    int wid = tid >> 6, lane = tid & 63;

#pragma unroll
    for (int sel = 0; sel < 2; sel++) {
        int b = sel ? bin1 : bin0;
        int s = binOff[b];
        int e = s + binCnt[b];
        float* ac = acc + sel * (SLICE * FEATDIM);
        for (int k = s + wid * 4; k < e; k += 16) {   // 4 waves x 4 edges ILP
#pragma unroll
            for (int u = 0; u < 4; u++) {
                int ei = k + u;
                int2 rec = (ei < e) ? binned[ei] : make_int2(0, 0);
                float v = __int_as_float(rec.y);
                int col = rec.x & 0x1FFFF;
                int row = rec.x >> 17;
                const float* xb = (col < nlo) ? xlo + (size_t)col * FEATDIM
                                              : xhi + (size_t)(col - nlo) * FEATDIM;
                float2 x2 = reinterpret_cast<const float2*>(xb)[lane];
                atomicAdd(&ac[row * FEATDIM + lane * 2],     v * x2.x);
                atomicAdd(&ac[row * FEATDIM + lane * 2 + 1], v * x2.y);
            }
        }
    }
    __syncthreads();

    // epilogue: out = 2*(relu(acc0)+relu(acc1)), routed per row
    int slice_base = slice * SLICE;
    int rmax = (isG1 ? N1 : N2) - slice_base;
    if (rmax > SLICE) rmax = SLICE;
    for (int idx = tid; idx < SLICE * (FEATDIM / 4); idx += 256) {
        int row = idx >> 5;
        int q   = idx & 31;
        if (row < rmax) {
            float4 a0 = reinterpret_cast<float4*>(acc)[row * 32 + q];
            float4 a1 = reinterpret_cast<float4*>(acc + SLICE * FEATDIM)[row * 32 + q];
            float4 res;
            res.x = 2.f * (fmaxf(a0.x, 0.f) + fmaxf(a1.x, 0.f));
            res.y = 2.f * (fmaxf(a0.y, 0.f) + fmaxf(a1.y, 0.f));
            res.z = 2.f * (fmaxf(a0.z, 0.f) + fmaxf(a1.z, 0.f));
            res.w = 2.f * (fmaxf(a0.w, 0.f) + fmaxf(a1.w, 0.f));
            int r = slice_base + row;
            float* dst;
            if (isG1) dst = (r < DIAGNUM) ? out_d + (size_t)r * FEATDIM
                                          : g1med + (size_t)(r - DIAGNUM) * FEATDIM;
            else      dst = (r < PRONUM)  ? out_p + (size_t)r * FEATDIM
                                          : g2med + (size_t)(r - PRONUM) * FEATDIM;
            reinterpret_cast<float4*>(dst)[q] = res;
        }
    }
}

// out_m = t*g1med + (1-t)*g2med
__global__ void combine_med_kernel(const float* __restrict__ g1med,
                                   const float* __restrict__ g2med,
                                   const float* __restrict__ inter,
                                   float* __restrict__ outm, long total_elems) {
    long i = ((long)blockIdx.x * blockDim.x + threadIdx.x) * 4;
    if (i >= total_elems) return;
    float t = *inter;
    float4 a = *reinterpret_cast<const float4*>(g1med + i);
    float4 b = *reinterpret_cast<const float4*>(g2med + i);
    float4 v;
    v.x = t * a.x + (1.0f - t) * b.x;
    v.y = t * a.y + (1.0f - t) * b.y;
    v.z = t * a.z + (1.0f - t) * b.z;
    v.w = t * a.w + (1.0f - t) * b.w;
    *reinterpret_cast<float4*>(outm + i) = v;
}

// ---------------- host orchestration ----------------

extern "C" void kernel_launch(void* const* d_in, const int* in_sizes, int n_in,
                              void* d_out, int out_size, void* d_ws, size_t ws_size,
                              hipStream_t stream) {
    const int*   a1r = (const int*)d_in[0];
    const int*   a1c = (const int*)d_in[1];
    const float* a1v = (const float*)d_in[2];
    const int*   a2r = (const int*)d_in[3];
    const int*   a2c = (const int*)d_in[4];
    const float* a2v = (const float*)d_in[5];
    const float* dE  = (const float*)d_in[6];
    const float* mE  = (const float*)d_in[7];
    const float* pE  = (const float*)d_in[8];
    const float* inter = (const float*)d_in[9];

    float* out   = (float*)d_out;
    float* out_m = out;                               // 20000*128
    float* out_d = out + (size_t)MEDNUM * FEATDIM;    // 50000*128
    float* out_p = out_d + (size_t)DIAGNUM * FEATDIM; // 40000*128

    // ws layout (~53.9 MB)
    char* ws = (char*)d_ws;
    float* g1med = (float*)ws;      ws += (size_t)MEDNUM * FEATDIM * 4;   // 10.24 MB
    float* g2med = (float*)ws;      ws += (size_t)MEDNUM * FEATDIM * 4;   // 10.24 MB
    int2*  binned = (int2*)ws;      ws += (size_t)NNZTOT * 8;             // 33.28 MB
    int*   binCnt = (int*)ws;       ws += (size_t)NBIN * 4;
    int*   binOff = (int*)ws;       ws += (size_t)NBIN * 4;
    int*   binCursor = (int*)ws;    ws += (size_t)NBIN * 4;

    const int BLK = 256;

    hipMemsetAsync(binCnt, 0, (size_t)NBIN * sizeof(int), stream);
    hist_bins_kernel<<<512, BLK, 0, stream>>>(a1r, a2r, binCnt);
    scan_bins_kernel<<<1, BLK, 0, stream>>>(binCnt, binOff, binCursor);
    binscatter_kernel<<<K2_BLOCKS, BLK, 0, stream>>>(a1r, a1c, a1v, a2r, a2c, a2v,
                                                     binCursor, binned);
    fused_lds_kernel<<<NB1 + NB2, BLK, 0, stream>>>(binned, binOff, binCnt,
                                                    dE, mE, pE,
                                                    out_d, g1med, out_p, g2med);

    long totm = (long)MEDNUM * FEATDIM;
    combine_med_kernel<<<(int)((totm / 4 + BLK - 1) / BLK), BLK, 0, stream>>>(
        g1med, g2med, inter, out_m, totm);
}

// Round 6
// 612.448 us; speedup vs baseline: 4.5943x; 4.5943x over previous
//
#include <hip/hip_runtime.h>

#define DIAGNUM 50000
#define MEDNUM  20000
#define PRONUM  40000
#define FEATDIM 128
#define N1 (DIAGNUM + MEDNUM)   // 70000
#define N2 (PRONUM + MEDNUM)    // 60000
#define NNZ1 1120000
#define NNZ2 960000
#define NTOT (2 * N1 + 2 * N2)            // 260000 concatenated rows
#define NNZTOT (2 * NNZ1 + 2 * NNZ2)      // 4160000 concatenated edges
#define SC_CHUNK 2048                      // edges per scatter block

typedef unsigned short ushort_t;

// round-to-nearest-even float -> bf16 (top 16 bits)
__device__ __forceinline__ unsigned f2bf(float f) {
    unsigned u = __float_as_uint(f);
    return (u + 0x7FFFu + ((u >> 16) & 1u)) >> 16;
}

// ---------------- bf16 embedding conversion ----------------
// embd=[dE], embm=[mE], embp=[pE] in bf16; 8 elems/thread
#define TOT8 ((DIAGNUM + MEDNUM + PRONUM) * (FEATDIM / 8))   // 1,760,000

__global__ __launch_bounds__(256) void convert_emb_kernel(
        const float* __restrict__ dE, const float* __restrict__ mE,
        const float* __restrict__ pE,
        ushort_t* __restrict__ embd, ushort_t* __restrict__ embm,
        ushort_t* __restrict__ embp) {
    int t8 = blockIdx.x * 256 + threadIdx.x;
    if (t8 >= TOT8) return;
    long flat = (long)t8 * 8;
    const float* src;
    ushort_t* dst;
    if (flat < (long)DIAGNUM * FEATDIM) {
        src = dE + flat;                          dst = embd + flat;
    } else if (flat < (long)(DIAGNUM + MEDNUM) * FEATDIM) {
        long o = flat - (long)DIAGNUM * FEATDIM;  src = mE + o; dst = embm + o;
    } else {
        long o = flat - (long)(DIAGNUM + MEDNUM) * FEATDIM;
        src = pE + o;                             dst = embp + o;
    }
    float4 a = *reinterpret_cast<const float4*>(src);
    float4 b = *reinterpret_cast<const float4*>(src + 4);
    int4 w;
    w.x = (int)(f2bf(a.x) | (f2bf(a.y) << 16));
    w.y = (int)(f2bf(a.z) | (f2bf(a.w) << 16));
    w.z = (int)(f2bf(b.x) | (f2bf(b.y) << 16));
    w.w = (int)(f2bf(b.z) | (f2bf(b.w) << 16));
    *reinterpret_cast<int4*>(dst) = w;
}

// ---------------- CSR construction ----------------

// counts = rpe+1, concatenated per-CSR row counts
__global__ void hist4_kernel(const int* __restrict__ a1r,
                             const int* __restrict__ a2r,
                             int* __restrict__ counts) {
    int i = blockIdx.x * blockDim.x + threadIdx.x;
    if (i >= NNZTOT) return;
    int idx;
    if (i < 2 * NNZ1) {
        idx = ((i < NNZ1) ? 0 : N1) + __builtin_nontemporal_load(a1r + i);
    } else {
        int j = i - 2 * NNZ1;
        idx = 2 * N1 + ((j < NNZ2) ? 0 : N2) + __builtin_nontemporal_load(a2r + j);
    }
    atomicAdd(&counts[idx], 1);
}

// chunk = 1024 elems per block (256 threads x 4)
__global__ void scan_reduce_kernel(const int* __restrict__ counts, int n,
                                   int* __restrict__ partials) {
    __shared__ int s[256];
    int t = threadIdx.x;
    int base = blockIdx.x * 1024 + t * 4;
    int sum = 0;
#pragma unroll
    for (int k = 0; k < 4; k++) {
        int idx = base + k;
        if (idx < n) sum += counts[idx];
    }
    s[t] = sum;
    __syncthreads();
    for (int off = 128; off > 0; off >>= 1) {
        if (t < off) s[t] += s[t + off];
        __syncthreads();
    }
    if (t == 0) partials[blockIdx.x] = s[0];
}

// single block: exclusive scan of partials[nchunks] (nchunks <= 256), in place
__global__ void scan_mid_kernel(int* __restrict__ partials, int nchunks) {
    __shared__ int s[256];
    int t = threadIdx.x;
    int v = (t < nchunks) ? partials[t] : 0;
    s[t] = v;
    __syncthreads();
    for (int off = 1; off < 256; off <<= 1) {
        int y = (t >= off) ? s[t - off] : 0;
        __syncthreads();
        s[t] += y;
        __syncthreads();
    }
    if (t < nchunks) partials[t] = s[t] - v;
}

// in-place: counts[i] -> exclusive prefix (start offset of row i)
__global__ void scan_apply_kernel(int* __restrict__ counts, int n,
                                  const int* __restrict__ partials) {
    __shared__ int s[256];
    int t = threadIdx.x;
    int base = blockIdx.x * 1024 + t * 4;
    int v[4];
    int sum = 0;
#pragma unroll
    for (int k = 0; k < 4; k++) {
        int idx = base + k;
        v[k] = (idx < n) ? counts[idx] : 0;
        sum += v[k];
    }
    s[t] = sum;
    __syncthreads();
    for (int off = 1; off < 256; off <<= 1) {
        int y = (t >= off) ? s[t - off] : 0;
        __syncthreads();
        s[t] += y;
        __syncthreads();
    }
    int excl = s[t] - sum;
    int run = partials[blockIdx.x] + excl;
#pragma unroll
    for (int k = 0; k < 4; k++) {
        int idx = base + k;
        if (idx < n) {
            counts[idx] = run;
            run += v[k];
        }
    }
}

// Single-pass XCD-sliced scatter. Destination space split into 8 contiguous
// row-slices; blocks with blockIdx%8==g write only slice g. blockIdx
// round-robins over 8 XCDs -> all writes to a slice come from ONE XCD's L2.
// Record: 4 bytes = (bf15(val) << 17) | col  (vals are positive; sign bit
// dropped; col < 2^17).
__global__ __launch_bounds__(256) void scatter_xcd_kernel(
        const int* __restrict__ a1r, const int* __restrict__ a1c,
        const float* __restrict__ a1v,
        const int* __restrict__ a2r, const int* __restrict__ a2c,
        const float* __restrict__ a2v,
        int* __restrict__ cursor,          // = rpe+1 (start offsets, mutated)
        int* __restrict__ binned) {
    int group = blockIdx.x & 7;
    int chunk = blockIdx.x >> 3;
    int base = chunk * SC_CHUNK + threadIdx.x;
#pragma unroll
    for (int u = 0; u < SC_CHUNK / 256; u++) {
        int i = base + u * 256;
        if (i < NNZTOT) {
            int idx, srcj;
            const int* rc;
            const float* rv;
            if (i < 2 * NNZ1) {
                srcj = i;
                idx = ((i < NNZ1) ? 0 : N1) + __builtin_nontemporal_load(a1r + srcj);
                rc = a1c; rv = a1v;
            } else {
                srcj = i - 2 * NNZ1;
                idx = 2 * N1 + ((srcj < NNZ2) ? 0 : N2) + __builtin_nontemporal_load(a2r + srcj);
                rc = a2c; rv = a2v;
            }
            int sl = (int)(((unsigned)idx * 8u) / (unsigned)NTOT);
            if (sl == group) {
                int   col = __builtin_nontemporal_load(rc + srcj);
                float val = __builtin_nontemporal_load(rv + srcj);
                int pos = atomicAdd(&cursor[idx], 1);
                unsigned bf15 = f2bf(val) & 0x7FFFu;
                binned[pos] = (int)((bf15 << 17) | (unsigned)col);
            }
        }
    }
}

// ---------------- fused GCN row kernel (bf16 gather) ----------------
// Half-wave scheme: 2 edges in flight, 32 lanes x 4 bf16 per edge.

__device__ __forceinline__ float4 row_gather(const int* __restrict__ rp,
                                             const int* __restrict__ binned,
                                             int half, int sub,
                                             const ushort_t* __restrict__ xlo,
                                             const ushort_t* __restrict__ xhi,
                                             int nlo) {
    int s = rp[0];
    int e = rp[1];
    float4 acc = make_float4(0.f, 0.f, 0.f, 0.f);
    for (int k = s + half; k < e; k += 2) {
        unsigned rec = (unsigned)binned[k];     // uniform across half-wave
        float v = __uint_as_float((rec >> 17) << 16);
        int col = (int)(rec & 0x1FFFFu);
        const ushort_t* xb = (col < nlo) ? xlo + (size_t)col * FEATDIM
                                         : xhi + (size_t)(col - nlo) * FEATDIM;
        ushort4 h = reinterpret_cast<const ushort4*>(xb)[sub];
        acc.x = fmaf(v, __uint_as_float((unsigned)h.x << 16), acc.x);
        acc.y = fmaf(v, __uint_as_float((unsigned)h.y << 16), acc.y);
        acc.z = fmaf(v, __uint_as_float((unsigned)h.z << 16), acc.z);
        acc.w = fmaf(v, __uint_as_float((unsigned)h.w << 16), acc.w);
    }
    return acc;
}

// one 64-lane wave per output row across BOTH graphs.
// Graph-1 med rows -> g1med (raw). Graph-2 med rows -> out_m scaled by (1-t).
__global__ __launch_bounds__(256) void fused_gcn2_kernel(
        const int* __restrict__ rpe,
        const int* __restrict__ binned,
        const ushort_t* __restrict__ embd, const ushort_t* __restrict__ embm,
        const ushort_t* __restrict__ embp,
        const float* __restrict__ inter,
        float* __restrict__ out_d, float* __restrict__ g1med,
        float* __restrict__ out_p, float* __restrict__ out_m) {
    int gtid = blockIdx.x * blockDim.x + threadIdx.x;
    int w    = gtid >> 6;
    int lane = gtid & 63;
    int half = lane >> 5;
    int sub  = lane & 31;
    if (w >= N1 + N2) return;

    const ushort_t *xlo, *xhi = embm;
    const int *rpA, *rpB;
    float* dst;
    int nlo;
    float sc = 1.0f;
    if (w < N1) {
        xlo = embd; nlo = DIAGNUM;
        rpA = rpe + w;
        rpB = rpe + N1 + w;
        dst = (w < DIAGNUM) ? out_d + (size_t)w * FEATDIM
                            : g1med + (size_t)(w - DIAGNUM) * FEATDIM;
    } else {
        int r = w - N1;
        xlo = embp; nlo = PRONUM;
        rpA = rpe + 2 * N1 + r;
        rpB = rpe + 2 * N1 + N2 + r;
        if (r < PRONUM) {
            dst = out_p + (size_t)r * FEATDIM;
        } else {
            dst = out_m + (size_t)(r - PRONUM) * FEATDIM;
            sc = 1.0f - *inter;
        }
    }

    float4 sA = row_gather(rpA, binned, half, sub, xlo, xhi, nlo);
    float4 sB = row_gather(rpB, binned, half, sub, xlo, xhi, nlo);

    float4 res;
    res.x = 2.f * sc * (fmaxf(sA.x + __shfl_xor(sA.x, 32), 0.f) +
                        fmaxf(sB.x + __shfl_xor(sB.x, 32), 0.f));
    res.y = 2.f * sc * (fmaxf(sA.y + __shfl_xor(sA.y, 32), 0.f) +
                        fmaxf(sB.y + __shfl_xor(sB.y, 32), 0.f));
    res.z = 2.f * sc * (fmaxf(sA.z + __shfl_xor(sA.z, 32), 0.f) +
                        fmaxf(sB.z + __shfl_xor(sB.z, 32), 0.f));
    res.w = 2.f * sc * (fmaxf(sA.w + __shfl_xor(sA.w, 32), 0.f) +
                        fmaxf(sB.w + __shfl_xor(sB.w, 32), 0.f));

    if (half == 0) {
        reinterpret_cast<float4*>(dst)[sub] = res;
    }
}

// out_m += t*g1med
__global__ void combine_med_kernel(const float* __restrict__ g1med,
                                   const float* __restrict__ inter,
                                   float* __restrict__ outm, long total_elems) {
    long i = ((long)blockIdx.x * blockDim.x + threadIdx.x) * 4;
    if (i >= total_elems) return;
    float t = *inter;
    float4 a = *reinterpret_cast<const float4*>(g1med + i);
    float4 o = *reinterpret_cast<const float4*>(outm + i);
    o.x = fmaf(t, a.x, o.x);
    o.y = fmaf(t, a.y, o.y);
    o.z = fmaf(t, a.z, o.z);
    o.w = fmaf(t, a.w, o.w);
    *reinterpret_cast<float4*>(outm + i) = o;
}

// ---------------- host orchestration ----------------

extern "C" void kernel_launch(void* const* d_in, const int* in_sizes, int n_in,
                              void* d_out, int out_size, void* d_ws, size_t ws_size,
                              hipStream_t stream) {
    const int*   a1r = (const int*)d_in[0];
    const int*   a1c = (const int*)d_in[1];
    const float* a1v = (const float*)d_in[2];
    const int*   a2r = (const int*)d_in[3];
    const int*   a2c = (const int*)d_in[4];
    const float* a2v = (const float*)d_in[5];
    const float* dE  = (const float*)d_in[6];
    const float* mE  = (const float*)d_in[7];
    const float* pE  = (const float*)d_in[8];
    const float* inter = (const float*)d_in[9];

    float* out   = (float*)d_out;
    float* out_m = out;                               // 20000*128
    float* out_d = out + (size_t)MEDNUM * FEATDIM;    // 50000*128
    float* out_p = out_d + (size_t)DIAGNUM * FEATDIM; // 40000*128

    // ws layout (~56.1 MB, 16B-aligned blocks)
    char* ws = (char*)d_ws;
    float*    g1med  = (float*)ws;    ws += (size_t)MEDNUM * FEATDIM * 4;    // 10.24 MB
    int*      binned = (int*)ws;      ws += (size_t)NNZTOT * 4;              // 16.64 MB
    ushort_t* embd   = (ushort_t*)ws; ws += (size_t)DIAGNUM * FEATDIM * 2;   // 12.80 MB
    ushort_t* embm   = (ushort_t*)ws; ws += (size_t)MEDNUM * FEATDIM * 2;    //  5.12 MB
    ushort_t* embp   = (ushort_t*)ws; ws += (size_t)PRONUM * FEATDIM * 2;    // 10.24 MB
    int*      rpe    = (int*)ws;      ws += (((size_t)(NTOT + 1) * 4 + 15) & ~15ull);
    int*      partials = (int*)ws;    ws += 256 * 4;

    const int BLK = 256;
    int nchunks = (NTOT + 1023) / 1024;   // 254

    convert_emb_kernel<<<(TOT8 + BLK - 1) / BLK, BLK, 0, stream>>>(
        dE, mE, pE, embd, embm, embp);

    // rpe[0] = 0, counts (rpe+1) = 0
    hipMemsetAsync(rpe, 0, (size_t)(NTOT + 1) * sizeof(int), stream);
    hist4_kernel<<<(NNZTOT + BLK - 1) / BLK, BLK, 0, stream>>>(a1r, a2r, rpe + 1);
    scan_reduce_kernel<<<nchunks, BLK, 0, stream>>>(rpe + 1, NTOT, partials);
    scan_mid_kernel<<<1, BLK, 0, stream>>>(partials, nchunks);
    scan_apply_kernel<<<nchunks, BLK, 0, stream>>>(rpe + 1, NTOT, partials);

    // single-pass XCD-sliced scatter (8 groups)
    int sc_chunks = (NNZTOT + SC_CHUNK - 1) / SC_CHUNK;   // 2032
    scatter_xcd_kernel<<<sc_chunks * 8, BLK, 0, stream>>>(
        a1r, a1c, a1v, a2r, a2c, a2v, rpe + 1, binned);

    // fused GCN over both graphs: one wave per row, 4 rows per block
    int nrows = N1 + N2;   // 130000
    fused_gcn2_kernel<<<(nrows + 3) / 4, BLK, 0, stream>>>(
        rpe, binned, embd, embm, embp, inter, out_d, g1med, out_p, out_m);

    long totm = (long)MEDNUM * FEATDIM;
    combine_med_kernel<<<(int)((totm / 4 + BLK - 1) / BLK), BLK, 0, stream>>>(
        g1med, inter, out_m, totm);
}

// Round 7
// 555.994 us; speedup vs baseline: 5.0608x; 1.1015x over previous
//
#include <hip/hip_runtime.h>

#define DIAGNUM 50000
#define MEDNUM  20000
#define PRONUM  40000
#define FEATDIM 128
#define N1 (DIAGNUM + MEDNUM)   // 70000
#define N2 (PRONUM + MEDNUM)    // 60000
#define NNZ1 1120000
#define NNZ2 960000
#define NTOT (2 * N1 + 2 * N2)            // 260000 concatenated rows
#define NNZTOT (2 * NNZ1 + 2 * NNZ2)      // 4160000 concatenated edges
#define SC_CHUNK 2048                      // edges per scatter block

typedef unsigned short ushort_t;

// round-to-nearest-even float -> bf16 (top 16 bits)
__device__ __forceinline__ unsigned f2bf(float f) {
    unsigned u = __float_as_uint(f);
    return (u + 0x7FFFu + ((u >> 16) & 1u)) >> 16;
}

// ---------------- bf16 embedding conversion ----------------
#define TOT8 ((DIAGNUM + MEDNUM + PRONUM) * (FEATDIM / 8))   // 1,760,000

__global__ __launch_bounds__(256) void convert_emb_kernel(
        const float* __restrict__ dE, const float* __restrict__ mE,
        const float* __restrict__ pE,
        ushort_t* __restrict__ embd, ushort_t* __restrict__ embm,
        ushort_t* __restrict__ embp) {
    int t8 = blockIdx.x * 256 + threadIdx.x;
    if (t8 >= TOT8) return;
    long flat = (long)t8 * 8;
    const float* src;
    ushort_t* dst;
    if (flat < (long)DIAGNUM * FEATDIM) {
        src = dE + flat;                          dst = embd + flat;
    } else if (flat < (long)(DIAGNUM + MEDNUM) * FEATDIM) {
        long o = flat - (long)DIAGNUM * FEATDIM;  src = mE + o; dst = embm + o;
    } else {
        long o = flat - (long)(DIAGNUM + MEDNUM) * FEATDIM;
        src = pE + o;                             dst = embp + o;
    }
    float4 a = *reinterpret_cast<const float4*>(src);
    float4 b = *reinterpret_cast<const float4*>(src + 4);
    int4 w;
    w.x = (int)(f2bf(a.x) | (f2bf(a.y) << 16));
    w.y = (int)(f2bf(a.z) | (f2bf(a.w) << 16));
    w.z = (int)(f2bf(b.x) | (f2bf(b.y) << 16));
    w.w = (int)(f2bf(b.z) | (f2bf(b.w) << 16));
    *reinterpret_cast<int4*>(dst) = w;
}

// ---------------- concatenated row index for edge i ----------------
__device__ __forceinline__ int edge_idx(int i, const int* __restrict__ a1r,
                                        const int* __restrict__ a2r) {
    if (i < 2 * NNZ1) {
        return ((i < NNZ1) ? 0 : N1) + a1r[i];
    } else {
        int j = i - 2 * NNZ1;
        return 2 * N1 + ((j < NNZ2) ? 0 : N2) + a2r[j];
    }
}

// ---------------- XCD-privatized histogram ----------------
// counts8[g][idx]: each block atomics only into copy g = blockIdx&7, which
// round-robins to its own XCD -> counter lines stay in the local L2.
__global__ __launch_bounds__(256) void hist8_kernel(const int* __restrict__ a1r,
                                                    const int* __restrict__ a2r,
                                                    int* __restrict__ counts8) {
    int i = blockIdx.x * 256 + threadIdx.x;
    if (i >= NNZTOT) return;
    int idx = edge_idx(i, a1r, a2r);
    atomicAdd(&counts8[(blockIdx.x & 7) * NTOT + idx], 1);
}

// ---------------- scan over summed counts8 ----------------
// chunk = 1024 rows per block (256 threads x 4)
__global__ __launch_bounds__(256) void scan_reduce_kernel(
        const int* __restrict__ counts8, int* __restrict__ partials) {
    __shared__ int s[256];
    int t = threadIdx.x;
    int base = blockIdx.x * 1024 + t * 4;
    int sum = 0;
#pragma unroll
    for (int k = 0; k < 4; k++) {
        int idx = base + k;
        if (idx < NTOT) {
            int c = 0;
#pragma unroll
            for (int g = 0; g < 8; g++) c += counts8[g * NTOT + idx];
            sum += c;
        }
    }
    s[t] = sum;
    __syncthreads();
    for (int off = 128; off > 0; off >>= 1) {
        if (t < off) s[t] += s[t + off];
        __syncthreads();
    }
    if (t == 0) partials[blockIdx.x] = s[0];
}

// single block: exclusive scan of partials[nchunks] (nchunks <= 256), in place
__global__ __launch_bounds__(256) void scan_mid_kernel(int* __restrict__ partials,
                                                       int nchunks) {
    __shared__ int s[256];
    int t = threadIdx.x;
    int v = (t < nchunks) ? partials[t] : 0;
    s[t] = v;
    __syncthreads();
    for (int off = 1; off < 256; off <<= 1) {
        int y = (t >= off) ? s[t - off] : 0;
        __syncthreads();
        s[t] += y;
        __syncthreads();
    }
    if (t < nchunks) partials[t] = s[t] - v;
}

// cursor[idx] = exclusive prefix (start offset of concatenated row idx)
__global__ __launch_bounds__(256) void scan_apply_kernel(
        const int* __restrict__ counts8, const int* __restrict__ partials,
        int* __restrict__ cursor) {
    __shared__ int s[256];
    int t = threadIdx.x;
    int base = blockIdx.x * 1024 + t * 4;
    int v[4];
    int sum = 0;
#pragma unroll
    for (int k = 0; k < 4; k++) {
        int idx = base + k;
        int c = 0;
        if (idx < NTOT) {
#pragma unroll
            for (int g = 0; g < 8; g++) c += counts8[g * NTOT + idx];
        }
        v[k] = c;
        sum += c;
    }
    s[t] = sum;
    __syncthreads();
    for (int off = 1; off < 256; off <<= 1) {
        int y = (t >= off) ? s[t - off] : 0;
        __syncthreads();
        s[t] += y;
        __syncthreads();
    }
    int excl = s[t] - sum;
    int run = partials[blockIdx.x] + excl;
#pragma unroll
    for (int k = 0; k < 4; k++) {
        int idx = base + k;
        if (idx < NTOT) {
            cursor[idx] = run;
            run += v[k];
        }
    }
}

// ---------------- XCD-sliced scatter, coalesced reads ----------------
// All of row/col/val are read unconditionally (coalesced); filter in-register.
// Blocks with blockIdx%8==g handle destination slice g (contiguous row range),
// so cursor atomics and binned writes stay in ONE XCD's L2.
// Record: 4 B = (bf15(val) << 17) | col   (vals positive, col < 2^17).
__global__ __launch_bounds__(256) void scatter_xcd_kernel(
        const int* __restrict__ a1r, const int* __restrict__ a1c,
        const float* __restrict__ a1v,
        const int* __restrict__ a2r, const int* __restrict__ a2c,
        const float* __restrict__ a2v,
        int* __restrict__ cursor,          // start offsets, mutated to ends
        int* __restrict__ binned) {
    int group = blockIdx.x & 7;
    int chunk = blockIdx.x >> 3;
    int base = chunk * SC_CHUNK + threadIdx.x;
#pragma unroll
    for (int u = 0; u < SC_CHUNK / 256; u++) {
        int i = base + u * 256;
        if (i < NNZTOT) {
            int idx, col;
            float val;
            if (i < 2 * NNZ1) {
                idx = ((i < NNZ1) ? 0 : N1) + a1r[i];
                col = a1c[i];
                val = a1v[i];
            } else {
                int j = i - 2 * NNZ1;
                idx = 2 * N1 + ((j < NNZ2) ? 0 : N2) + a2r[j];
                col = a2c[j];
                val = a2v[j];
            }
            int sl = (int)(((unsigned)idx * 8u) / (unsigned)NTOT);
            if (sl == group) {
                int pos = atomicAdd(&cursor[idx], 1);
                unsigned bf15 = f2bf(val) & 0x7FFFu;
                binned[pos] = (int)((bf15 << 17) | (unsigned)col);
            }
        }
    }
}

// ---------------- fused GCN row kernel (bf16 gather, 2x unrolled) ----------------

__device__ __forceinline__ const ushort_t* col_base(unsigned rec, int nlo,
                                                    const ushort_t* __restrict__ xlo,
                                                    const ushort_t* __restrict__ xhi) {
    int col = (int)(rec & 0x1FFFFu);
    return (col < nlo) ? xlo + (size_t)col * FEATDIM
                       : xhi + (size_t)(col - nlo) * FEATDIM;
}

__device__ __forceinline__ void fma4(float4& acc, float v, ushort4 h) {
    acc.x = fmaf(v, __uint_as_float((unsigned)h.x << 16), acc.x);
    acc.y = fmaf(v, __uint_as_float((unsigned)h.y << 16), acc.y);
    acc.z = fmaf(v, __uint_as_float((unsigned)h.z << 16), acc.z);
    acc.w = fmaf(v, __uint_as_float((unsigned)h.w << 16), acc.w);
}

__device__ __forceinline__ float4 row_gather(int s, int e,
                                             const int* __restrict__ binned,
                                             int half, int sub,
                                             const ushort_t* __restrict__ xlo,
                                             const ushort_t* __restrict__ xhi,
                                             int nlo) {
    float4 acc = make_float4(0.f, 0.f, 0.f, 0.f);
    int k = s + half;
    for (; k + 2 < e; k += 4) {
        unsigned r0 = (unsigned)binned[k];
        unsigned r1 = (unsigned)binned[k + 2];
        const ushort_t* b0 = col_base(r0, nlo, xlo, xhi);
        const ushort_t* b1 = col_base(r1, nlo, xlo, xhi);
        ushort4 h0 = reinterpret_cast<const ushort4*>(b0)[sub];
        ushort4 h1 = reinterpret_cast<const ushort4*>(b1)[sub];
        fma4(acc, __uint_as_float((r0 >> 17) << 16), h0);
        fma4(acc, __uint_as_float((r1 >> 17) << 16), h1);
    }
    if (k < e) {
        unsigned r0 = (unsigned)binned[k];
        const ushort_t* b0 = col_base(r0, nlo, xlo, xhi);
        ushort4 h0 = reinterpret_cast<const ushort4*>(b0)[sub];
        fma4(acc, __uint_as_float((r0 >> 17) << 16), h0);
    }
    return acc;
}

// One 64-lane wave per output row of ONE graph.
// graph==0 (graph2): med rows -> out_m = (1-t)*res (pure write)
// graph==1 (graph1): med rows -> out_m += t*res    (after graph2 launch)
__global__ __launch_bounds__(256) void fused_gcn_kernel(
        const int* __restrict__ rpe,
        const int* __restrict__ binned,
        const ushort_t* __restrict__ embd, const ushort_t* __restrict__ embm,
        const ushort_t* __restrict__ embp,
        const float* __restrict__ inter,
        float* __restrict__ out_d, float* __restrict__ out_p,
        float* __restrict__ out_m, int graph) {
    int gtid = blockIdx.x * blockDim.x + threadIdx.x;
    int w    = gtid >> 6;
    int lane = gtid & 63;
    int half = lane >> 5;
    int sub  = lane & 31;

    const ushort_t *xlo, *xhi = embm;
    const int *rpA, *rpB;
    int nlo, nrows;
    if (graph) { xlo = embd; nlo = DIAGNUM; nrows = N1;
                 rpA = rpe + w; rpB = rpe + N1 + w; }
    else       { xlo = embp; nlo = PRONUM;  nrows = N2;
                 rpA = rpe + 2 * N1 + w; rpB = rpe + 2 * N1 + N2 + w; }
    if (w >= nrows) return;

    // row spans: start = rpe[...-1+1]=rpe[idx], end = rpe[idx+1] (post-scatter)
    int sA = rpA[0], eA = rpA[1];
    int sB = rpB[0], eB = rpB[1];

    float4 vA = row_gather(sA, eA, binned, half, sub, xlo, xhi, nlo);
    float4 vB = row_gather(sB, eB, binned, half, sub, xlo, xhi, nlo);

    float4 res;
    res.x = 2.f * (fmaxf(vA.x + __shfl_xor(vA.x, 32), 0.f) +
                   fmaxf(vB.x + __shfl_xor(vB.x, 32), 0.f));
    res.y = 2.f * (fmaxf(vA.y + __shfl_xor(vA.y, 32), 0.f) +
                   fmaxf(vB.y + __shfl_xor(vB.y, 32), 0.f));
    res.z = 2.f * (fmaxf(vA.z + __shfl_xor(vA.z, 32), 0.f) +
                   fmaxf(vB.z + __shfl_xor(vB.z, 32), 0.f));
    res.w = 2.f * (fmaxf(vA.w + __shfl_xor(vA.w, 32), 0.f) +
                   fmaxf(vB.w + __shfl_xor(vB.w, 32), 0.f));

    if (half != 0) return;

    if (graph) {
        if (w < DIAGNUM) {
            reinterpret_cast<float4*>(out_d + (size_t)w * FEATDIM)[sub] = res;
        } else {
            float t = *inter;
            float4* dst = reinterpret_cast<float4*>(
                out_m + (size_t)(w - DIAGNUM) * FEATDIM);
            float4 o = dst[sub];
            o.x = fmaf(t, res.x, o.x);
            o.y = fmaf(t, res.y, o.y);
            o.z = fmaf(t, res.z, o.z);
            o.w = fmaf(t, res.w, o.w);
            dst[sub] = o;
        }
    } else {
        if (w < PRONUM) {
            reinterpret_cast<float4*>(out_p + (size_t)w * FEATDIM)[sub] = res;
        } else {
            float sc = 1.0f - *inter;
            res.x *= sc; res.y *= sc; res.z *= sc; res.w *= sc;
            reinterpret_cast<float4*>(out_m + (size_t)(w - PRONUM) * FEATDIM)[sub] = res;
        }
    }
}

// ---------------- host orchestration ----------------

extern "C" void kernel_launch(void* const* d_in, const int* in_sizes, int n_in,
                              void* d_out, int out_size, void* d_ws, size_t ws_size,
                              hipStream_t stream) {
    const int*   a1r = (const int*)d_in[0];
    const int*   a1c = (const int*)d_in[1];
    const float* a1v = (const float*)d_in[2];
    const int*   a2r = (const int*)d_in[3];
    const int*   a2c = (const int*)d_in[4];
    const float* a2v = (const float*)d_in[5];
    const float* dE  = (const float*)d_in[6];
    const float* mE  = (const float*)d_in[7];
    const float* pE  = (const float*)d_in[8];
    const float* inter = (const float*)d_in[9];

    float* out   = (float*)d_out;
    float* out_m = out;                               // 20000*128
    float* out_d = out + (size_t)MEDNUM * FEATDIM;    // 50000*128
    float* out_p = out_d + (size_t)DIAGNUM * FEATDIM; // 40000*128

    // ws layout (~54.2 MB, 16B-aligned blocks)
    char* ws = (char*)d_ws;
    int*      binned  = (int*)ws;      ws += (size_t)NNZTOT * 4;              // 16.64 MB
    ushort_t* embd    = (ushort_t*)ws; ws += (size_t)DIAGNUM * FEATDIM * 2;   // 12.80 MB
    ushort_t* embm    = (ushort_t*)ws; ws += (size_t)MEDNUM * FEATDIM * 2;    //  5.12 MB
    ushort_t* embp    = (ushort_t*)ws; ws += (size_t)PRONUM * FEATDIM * 2;    // 10.24 MB
    int*      counts8 = (int*)ws;      ws += (size_t)8 * NTOT * 4;            //  8.32 MB
    int*      rpe     = (int*)ws;      ws += (((size_t)(NTOT + 1) * 4 + 15) & ~15ull);
    int*      partials = (int*)ws;     ws += 256 * 4;

    const int BLK = 256;
    int nchunks = (NTOT + 1023) / 1024;   // 254

    convert_emb_kernel<<<(TOT8 + BLK - 1) / BLK, BLK, 0, stream>>>(
        dE, mE, pE, embd, embm, embp);

    hipMemsetAsync(counts8, 0, (size_t)8 * NTOT * sizeof(int), stream);
    hipMemsetAsync(rpe, 0, sizeof(int), stream);   // rpe[0] = 0

    hist8_kernel<<<(NNZTOT + BLK - 1) / BLK, BLK, 0, stream>>>(a1r, a2r, counts8);
    scan_reduce_kernel<<<nchunks, BLK, 0, stream>>>(counts8, partials);
    scan_mid_kernel<<<1, BLK, 0, stream>>>(partials, nchunks);
    scan_apply_kernel<<<nchunks, BLK, 0, stream>>>(counts8, partials, rpe + 1);

    // XCD-sliced scatter (8 groups, coalesced reads)
    int sc_chunks = (NNZTOT + SC_CHUNK - 1) / SC_CHUNK;   // 2032
    scatter_xcd_kernel<<<sc_chunks * 8, BLK, 0, stream>>>(
        a1r, a1c, a1v, a2r, a2c, a2v, rpe + 1, binned);

    // graph 2 first (writes out_m pure), then graph 1 (accumulates out_m)
    fused_gcn_kernel<<<(N2 + 3) / 4, BLK, 0, stream>>>(
        rpe, binned, embd, embm, embp, inter, out_d, out_p, out_m, 0);
    fused_gcn_kernel<<<(N1 + 3) / 4, BLK, 0, stream>>>(
        rpe, binned, embd, embm, embp, inter, out_d, out_p, out_m, 1);
}

// Round 8
// 300.953 us; speedup vs baseline: 9.3495x; 1.8474x over previous
//
#include <hip/hip_runtime.h>

#define DIAGNUM 50000
#define MEDNUM  20000
#define PRONUM  40000
#define FEATDIM 128
#define N1 (DIAGNUM + MEDNUM)   // 70000
#define N2 (PRONUM + MEDNUM)    // 60000
#define NNZ1 1120000
#define NNZ2 960000
#define NTOT (2 * N1 + 2 * N2)            // 260000 concatenated rows
#define NNZTOT (2 * NNZ1 + 2 * NNZ2)      // 4160000 concatenated edges
#define NBUCK ((NTOT + 255) >> 8)         // 1016 buckets of 256 rows
#define L1_CHUNK 16384
#define L1_BLOCKS ((NNZTOT + L1_CHUNK - 1) / L1_CHUNK)   // 254

typedef unsigned short ushort_t;

// round-to-nearest-even float -> bf16 (top 16 bits)
__device__ __forceinline__ unsigned f2bf(float f) {
    unsigned u = __float_as_uint(f);
    return (u + 0x7FFFu + ((u >> 16) & 1u)) >> 16;
}

// concatenated row index for edge i
__device__ __forceinline__ int edge_idx(int i, const int* __restrict__ a1r,
                                        const int* __restrict__ a2r) {
    if (i < 2 * NNZ1) {
        return ((i < NNZ1) ? 0 : N1) + a1r[i];
    } else {
        int j = i - 2 * NNZ1;
        return 2 * N1 + ((j < NNZ2) ? 0 : N2) + a2r[j];
    }
}

// ---------------- bucket count ----------------
__global__ __launch_bounds__(256) void count_buckets_kernel(
        const int* __restrict__ a1r, const int* __restrict__ a2r,
        int* __restrict__ bucketCnt) {
    __shared__ int lh[NBUCK];
    for (int b = threadIdx.x; b < NBUCK; b += 256) lh[b] = 0;
    __syncthreads();
    int stride = gridDim.x * 256;
    for (int i = blockIdx.x * 256 + threadIdx.x; i < NNZTOT; i += stride)
        atomicAdd(&lh[edge_idx(i, a1r, a2r) >> 8], 1);
    __syncthreads();
    for (int b = threadIdx.x; b < NBUCK; b += 256) {
        int h = lh[b];
        if (h) atomicAdd(&bucketCnt[b], h);
    }
}

// ---------------- exclusive scan of bucket counts (single block) ----------------
__global__ __launch_bounds__(256) void scan_buckets_kernel(
        const int* __restrict__ bucketCnt, int* __restrict__ bucketOff,
        int* __restrict__ cursor) {
    __shared__ int s[256];
    int t = threadIdx.x;
    int vals[4];
    int sum = 0;
#pragma unroll
    for (int k = 0; k < 4; k++) {
        int b = t * 4 + k;
        vals[k] = (b < NBUCK) ? bucketCnt[b] : 0;
        sum += vals[k];
    }
    s[t] = sum;
    __syncthreads();
    for (int off = 1; off < 256; off <<= 1) {
        int y = (t >= off) ? s[t - off] : 0;
        __syncthreads();
        s[t] += y;
        __syncthreads();
    }
    int run = s[t] - sum;
#pragma unroll
    for (int k = 0; k < 4; k++) {
        int b = t * 4 + k;
        if (b < NBUCK) {
            bucketOff[b] = run;
            cursor[b] = run;
            run += vals[k];
        }
    }
    if (t == 255) bucketOff[NBUCK] = run;   // == NNZTOT
}

// ---------------- level-1 scatter into coarse buckets ----------------
// record: .x = (row_local << 17) | col   (row_local 8b, col 17b), .y = val bits
__global__ __launch_bounds__(256) void lvl1_scatter_kernel(
        const int* __restrict__ a1r, const int* __restrict__ a1c,
        const float* __restrict__ a1v,
        const int* __restrict__ a2r, const int* __restrict__ a2c,
        const float* __restrict__ a2v,
        int* __restrict__ cursor, int2* __restrict__ lvl1) {
    __shared__ int lh[NBUCK];
    for (int b = threadIdx.x; b < NBUCK; b += 256) lh[b] = 0;
    __syncthreads();
    int base = blockIdx.x * L1_CHUNK;
    int end  = min(base + L1_CHUNK, NNZTOT);
    // sweep 1: block-local bucket histogram
    for (int i = base + threadIdx.x; i < end; i += 256)
        atomicAdd(&lh[edge_idx(i, a1r, a2r) >> 8], 1);
    __syncthreads();
    // reserve spans: lh[b] becomes this block's rolling global cursor
    for (int b = threadIdx.x; b < NBUCK; b += 256) {
        int h = lh[b];
        lh[b] = h ? atomicAdd(&cursor[b], h) : 0;
    }
    __syncthreads();
    // sweep 2: write records
    for (int i = base + threadIdx.x; i < end; i += 256) {
        int idx, col;
        float val;
        if (i < 2 * NNZ1) {
            idx = ((i < NNZ1) ? 0 : N1) + a1r[i];
            col = a1c[i];
            val = a1v[i];
        } else {
            int j = i - 2 * NNZ1;
            idx = 2 * N1 + ((j < NNZ2) ? 0 : N2) + a2r[j];
            col = a2c[j];
            val = a2v[j];
        }
        int pos = atomicAdd(&lh[idx >> 8], 1);
        lvl1[pos] = make_int2(((idx & 255) << 17) | col, __float_as_int(val));
    }
}

// ---------------- level-2 sort within bucket (one block per bucket) ----------------
// Block exclusively owns its ~16 KB destination range -> clean full-line writes.
// Also writes rpe[idx+1] = row end offsets.
__global__ __launch_bounds__(256) void lvl2_sort_kernel(
        const int2* __restrict__ lvl1, const int* __restrict__ bucketOff,
        int* __restrict__ binned, int* __restrict__ rpe) {
    __shared__ int cnt[256];
    __shared__ int sc[256];
    int b = blockIdx.x;
    int t = threadIdx.x;
    int s0 = bucketOff[b];
    int e0 = bucketOff[b + 1];
    cnt[t] = 0;
    __syncthreads();
    for (int k = s0 + t; k < e0; k += 256)
        atomicAdd(&cnt[lvl1[k].x >> 17], 1);
    __syncthreads();
    int v = cnt[t];
    sc[t] = v;
    __syncthreads();
    for (int off = 1; off < 256; off <<= 1) {
        int y = (t >= off) ? sc[t - off] : 0;
        __syncthreads();
        sc[t] += y;
        __syncthreads();
    }
    int incl = sc[t];
    int excl = incl - v;
    int idx = (b << 8) + t;
    if (idx < NTOT) rpe[idx + 1] = s0 + incl;
    cnt[t] = excl;   // repurpose as local cursor
    __syncthreads();
    for (int k = s0 + t; k < e0; k += 256) {
        int2 rec = lvl1[k];
        int rl  = rec.x >> 17;
        int col = rec.x & 0x1FFFF;
        unsigned bf15 = f2bf(__int_as_float(rec.y)) & 0x7FFFu;
        int pos = atomicAdd(&cnt[rl], 1);
        binned[s0 + pos] = (int)((bf15 << 17) | (unsigned)col);
    }
}

// ---------------- bf16 embedding conversion ----------------
#define TOT8 ((DIAGNUM + MEDNUM + PRONUM) * (FEATDIM / 8))   // 1,760,000

__global__ __launch_bounds__(256) void convert_emb_kernel(
        const float* __restrict__ dE, const float* __restrict__ mE,
        const float* __restrict__ pE,
        ushort_t* __restrict__ embd, ushort_t* __restrict__ embm,
        ushort_t* __restrict__ embp) {
    int t8 = blockIdx.x * 256 + threadIdx.x;
    if (t8 >= TOT8) return;
    long flat = (long)t8 * 8;
    const float* src;
    ushort_t* dst;
    if (flat < (long)DIAGNUM * FEATDIM) {
        src = dE + flat;                          dst = embd + flat;
    } else if (flat < (long)(DIAGNUM + MEDNUM) * FEATDIM) {
        long o = flat - (long)DIAGNUM * FEATDIM;  src = mE + o; dst = embm + o;
    } else {
        long o = flat - (long)(DIAGNUM + MEDNUM) * FEATDIM;
        src = pE + o;                             dst = embp + o;
    }
    float4 a = *reinterpret_cast<const float4*>(src);
    float4 b = *reinterpret_cast<const float4*>(src + 4);
    int4 w;
    w.x = (int)(f2bf(a.x) | (f2bf(a.y) << 16));
    w.y = (int)(f2bf(a.z) | (f2bf(a.w) << 16));
    w.z = (int)(f2bf(b.x) | (f2bf(b.y) << 16));
    w.w = (int)(f2bf(b.z) | (f2bf(b.w) << 16));
    *reinterpret_cast<int4*>(dst) = w;
}

// ---------------- fused GCN row kernel (quarter-wave bf16 gather) ----------------
// 16 lanes x ushort8 (16 B) per edge, 4 edges in flight per wave.

__device__ __forceinline__ void gather8(int s, int e,
                                        const int* __restrict__ binned,
                                        int q, int sub16,
                                        const ushort_t* __restrict__ xlo,
                                        const ushort_t* __restrict__ xhi,
                                        int nlo, float acc[8]) {
    for (int k = s + q; k < e; k += 4) {
        unsigned rec = (unsigned)binned[k];
        float v = __uint_as_float((rec >> 17) << 16);
        int col = (int)(rec & 0x1FFFFu);
        const ushort_t* xb = (col < nlo) ? xlo + (size_t)col * FEATDIM
                                         : xhi + (size_t)(col - nlo) * FEATDIM;
        int4 h = reinterpret_cast<const int4*>(xb)[sub16];
        acc[0] = fmaf(v, __uint_as_float((unsigned)h.x << 16), acc[0]);
        acc[1] = fmaf(v, __uint_as_float((unsigned)h.x & 0xFFFF0000u), acc[1]);
        acc[2] = fmaf(v, __uint_as_float((unsigned)h.y << 16), acc[2]);
        acc[3] = fmaf(v, __uint_as_float((unsigned)h.y & 0xFFFF0000u), acc[3]);
        acc[4] = fmaf(v, __uint_as_float((unsigned)h.z << 16), acc[4]);
        acc[5] = fmaf(v, __uint_as_float((unsigned)h.z & 0xFFFF0000u), acc[5]);
        acc[6] = fmaf(v, __uint_as_float((unsigned)h.w << 16), acc[6]);
        acc[7] = fmaf(v, __uint_as_float((unsigned)h.w & 0xFFFF0000u), acc[7]);
    }
}

// One 64-lane wave per output row of ONE graph.
// graph==0 (graph2): med rows -> out_m = (1-t)*res (pure write)
// graph==1 (graph1): med rows -> out_m += t*res    (after graph2 launch)
__global__ __launch_bounds__(256) void fused_gcn_kernel(
        const int* __restrict__ rpe,
        const int* __restrict__ binned,
        const ushort_t* __restrict__ embd, const ushort_t* __restrict__ embm,
        const ushort_t* __restrict__ embp,
        const float* __restrict__ inter,
        float* __restrict__ out_d, float* __restrict__ out_p,
        float* __restrict__ out_m, int graph) {
    int gtid = blockIdx.x * blockDim.x + threadIdx.x;
    int w     = gtid >> 6;
    int lane  = gtid & 63;
    int q     = lane >> 4;
    int sub16 = lane & 15;

    const ushort_t *xlo, *xhi = embm;
    const int *rpA, *rpB;
    int nlo, nrows;
    if (graph) { xlo = embd; nlo = DIAGNUM; nrows = N1;
                 rpA = rpe + w; rpB = rpe + N1 + w; }
    else       { xlo = embp; nlo = PRONUM;  nrows = N2;
                 rpA = rpe + 2 * N1 + w; rpB = rpe + 2 * N1 + N2 + w; }
    if (w >= nrows) return;

    float aA[8] = {0, 0, 0, 0, 0, 0, 0, 0};
    float aB[8] = {0, 0, 0, 0, 0, 0, 0, 0};
    gather8(rpA[0], rpA[1], binned, q, sub16, xlo, xhi, nlo, aA);
    gather8(rpB[0], rpB[1], binned, q, sub16, xlo, xhi, nlo, aB);

    // reduce the 4 quarters
#pragma unroll
    for (int j = 0; j < 8; j++) {
        aA[j] += __shfl_xor(aA[j], 16);
        aA[j] += __shfl_xor(aA[j], 32);
        aB[j] += __shfl_xor(aB[j], 16);
        aB[j] += __shfl_xor(aB[j], 32);
    }

    if (lane >= 16) return;

    float r[8];
#pragma unroll
    for (int j = 0; j < 8; j++)
        r[j] = 2.f * (fmaxf(aA[j], 0.f) + fmaxf(aB[j], 0.f));

    float4 lo = make_float4(r[0], r[1], r[2], r[3]);
    float4 hi = make_float4(r[4], r[5], r[6], r[7]);

    if (graph) {
        if (w < DIAGNUM) {
            float4* dst = reinterpret_cast<float4*>(out_d + (size_t)w * FEATDIM);
            dst[sub16 * 2]     = lo;
            dst[sub16 * 2 + 1] = hi;
        } else {
            float t = *inter;
            float4* dst = reinterpret_cast<float4*>(
                out_m + (size_t)(w - DIAGNUM) * FEATDIM);
            float4 o0 = dst[sub16 * 2];
            float4 o1 = dst[sub16 * 2 + 1];
            o0.x = fmaf(t, lo.x, o0.x); o0.y = fmaf(t, lo.y, o0.y);
            o0.z = fmaf(t, lo.z, o0.z); o0.w = fmaf(t, lo.w, o0.w);
            o1.x = fmaf(t, hi.x, o1.x); o1.y = fmaf(t, hi.y, o1.y);
            o1.z = fmaf(t, hi.z, o1.z); o1.w = fmaf(t, hi.w, o1.w);
            dst[sub16 * 2]     = o0;
            dst[sub16 * 2 + 1] = o1;
        }
    } else {
        if (w < PRONUM) {
            float4* dst = reinterpret_cast<float4*>(out_p + (size_t)w * FEATDIM);
            dst[sub16 * 2]     = lo;
            dst[sub16 * 2 + 1] = hi;
        } else {
            float sc = 1.0f - *inter;
            lo.x *= sc; lo.y *= sc; lo.z *= sc; lo.w *= sc;
            hi.x *= sc; hi.y *= sc; hi.z *= sc; hi.w *= sc;
            float4* dst = reinterpret_cast<float4*>(
                out_m + (size_t)(w - PRONUM) * FEATDIM);
            dst[sub16 * 2]     = lo;
            dst[sub16 * 2 + 1] = hi;
        }
    }
}

// ---------------- host orchestration ----------------

extern "C" void kernel_launch(void* const* d_in, const int* in_sizes, int n_in,
                              void* d_out, int out_size, void* d_ws, size_t ws_size,
                              hipStream_t stream) {
    const int*   a1r = (const int*)d_in[0];
    const int*   a1c = (const int*)d_in[1];
    const float* a1v = (const float*)d_in[2];
    const int*   a2r = (const int*)d_in[3];
    const int*   a2c = (const int*)d_in[4];
    const float* a2v = (const float*)d_in[5];
    const float* dE  = (const float*)d_in[6];
    const float* mE  = (const float*)d_in[7];
    const float* pE  = (const float*)d_in[8];
    const float* inter = (const float*)d_in[9];

    float* out   = (float*)d_out;
    float* out_m = out;                               // 20000*128
    float* out_d = out + (size_t)MEDNUM * FEATDIM;    // 50000*128
    float* out_p = out_d + (size_t)DIAGNUM * FEATDIM; // 40000*128

    // ws layout (~51 MB). regionB is time-shared: lvl1 records (phase 1) then
    // bf16 embeddings (phase 2) — lvl1 is dead before convert_emb runs.
    char* ws = (char*)d_ws;
    int* binned = (int*)ws;          ws += (size_t)NNZTOT * 4;          // 16.64 MB
    char* regionB = ws;              ws += (size_t)NNZTOT * 8;          // 33.28 MB
    int2*     lvl1 = (int2*)regionB;
    ushort_t* embd = (ushort_t*)regionB;
    ushort_t* embm = embd + (size_t)DIAGNUM * FEATDIM;
    ushort_t* embp = embm + (size_t)MEDNUM * FEATDIM;
    int* rpe       = (int*)ws;       ws += (((size_t)(NTOT + 1) * 4 + 15) & ~15ull);
    int* bucketCnt = (int*)ws;       ws += (size_t)NBUCK * 4;
    int* bucketOff = (int*)ws;       ws += (size_t)(NBUCK + 1) * 4;
    int* cursor    = (int*)ws;       ws += (size_t)NBUCK * 4;

    const int BLK = 256;

    hipMemsetAsync(bucketCnt, 0, (size_t)NBUCK * sizeof(int), stream);
    hipMemsetAsync(rpe, 0, sizeof(int), stream);   // rpe[0] = 0

    count_buckets_kernel<<<512, BLK, 0, stream>>>(a1r, a2r, bucketCnt);
    scan_buckets_kernel<<<1, BLK, 0, stream>>>(bucketCnt, bucketOff, cursor);
    lvl1_scatter_kernel<<<L1_BLOCKS, BLK, 0, stream>>>(
        a1r, a1c, a1v, a2r, a2c, a2v, cursor, lvl1);
    lvl2_sort_kernel<<<NBUCK, BLK, 0, stream>>>(lvl1, bucketOff, binned, rpe);

    convert_emb_kernel<<<(TOT8 + BLK - 1) / BLK, BLK, 0, stream>>>(
        dE, mE, pE, embd, embm, embp);

    // graph 2 first (writes out_m pure), then graph 1 (accumulates out_m)
    fused_gcn_kernel<<<(N2 + 3) / 4, BLK, 0, stream>>>(
        rpe, binned, embd, embm, embp, inter, out_d, out_p, out_m, 0);
    fused_gcn_kernel<<<(N1 + 3) / 4, BLK, 0, stream>>>(
        rpe, binned, embd, embm, embp, inter, out_d, out_p, out_m, 1);
}

// Round 9
// 257.102 us; speedup vs baseline: 10.9441x; 1.1706x over previous
//
#include <hip/hip_runtime.h>

#define DIAGNUM 50000
#define MEDNUM  20000
#define PRONUM  40000
#define FEATDIM 128
#define N1 (DIAGNUM + MEDNUM)   // 70000
#define N2 (PRONUM + MEDNUM)    // 60000
#define NNZ1 1120000
#define NNZ2 960000
#define NTOT (2 * N1 + 2 * N2)            // 260000 concatenated rows
#define NNZTOT (2 * NNZ1 + 2 * NNZ2)      // 4160000 concatenated edges
#define NBUCK ((NTOT + 255) >> 8)         // 1016 buckets of 256 rows
#define L1_THREADS 512
#define L1_CHUNK 8192
#define L1_BLOCKS ((NNZTOT + L1_CHUNK - 1) / L1_CHUNK)   // 508

typedef unsigned short ushort_t;

// round-to-nearest-even float -> bf16 (top 16 bits)
__device__ __forceinline__ unsigned f2bf(float f) {
    unsigned u = __float_as_uint(f);
    return (u + 0x7FFFu + ((u >> 16) & 1u)) >> 16;
}

// concatenated row index for edge i
__device__ __forceinline__ int edge_idx(int i, const int* __restrict__ a1r,
                                        const int* __restrict__ a2r) {
    if (i < 2 * NNZ1) {
        return ((i < NNZ1) ? 0 : N1) + a1r[i];
    } else {
        int j = i - 2 * NNZ1;
        return 2 * N1 + ((j < NNZ2) ? 0 : N2) + a2r[j];
    }
}

// ---------------- bucket count ----------------
__global__ __launch_bounds__(256) void count_buckets_kernel(
        const int* __restrict__ a1r, const int* __restrict__ a2r,
        int* __restrict__ bucketCnt) {
    __shared__ int lh[NBUCK];
    for (int b = threadIdx.x; b < NBUCK; b += 256) lh[b] = 0;
    __syncthreads();
    int stride = gridDim.x * 256;
    for (int i = blockIdx.x * 256 + threadIdx.x; i < NNZTOT; i += stride)
        atomicAdd(&lh[edge_idx(i, a1r, a2r) >> 8], 1);
    __syncthreads();
    for (int b = threadIdx.x; b < NBUCK; b += 256) {
        int h = lh[b];
        if (h) atomicAdd(&bucketCnt[b], h);
    }
}

// ---------------- exclusive scan of bucket counts (single block) ----------------
__global__ __launch_bounds__(256) void scan_buckets_kernel(
        const int* __restrict__ bucketCnt, int* __restrict__ bucketOff,
        int* __restrict__ cursor) {
    __shared__ int s[256];
    int t = threadIdx.x;
    int vals[4];
    int sum = 0;
#pragma unroll
    for (int k = 0; k < 4; k++) {
        int b = t * 4 + k;
        vals[k] = (b < NBUCK) ? bucketCnt[b] : 0;
        sum += vals[k];
    }
    s[t] = sum;
    __syncthreads();
    for (int off = 1; off < 256; off <<= 1) {
        int y = (t >= off) ? s[t - off] : 0;
        __syncthreads();
        s[t] += y;
        __syncthreads();
    }
    int run = s[t] - sum;
#pragma unroll
    for (int k = 0; k < 4; k++) {
        int b = t * 4 + k;
        if (b < NBUCK) {
            bucketOff[b] = run;
            cursor[b] = run;
            run += vals[k];
        }
    }
    if (t == 255) bucketOff[NBUCK] = run;   // == NNZTOT
}

// ---------------- level-1 scatter into coarse buckets ----------------
// 512 threads x 8192-edge chunks: 16 waves/CU (was 4), per-bucket runs still
// ~8 edges = 64 B = one full line.
// record: .x = (row_local << 17) | col   (row_local 8b, col 17b), .y = val bits
__global__ __launch_bounds__(L1_THREADS) void lvl1_scatter_kernel(
        const int* __restrict__ a1r, const int* __restrict__ a1c,
        const float* __restrict__ a1v,
        const int* __restrict__ a2r, const int* __restrict__ a2c,
        const float* __restrict__ a2v,
        int* __restrict__ cursor, int2* __restrict__ lvl1) {
    __shared__ int lh[NBUCK];
    for (int b = threadIdx.x; b < NBUCK; b += L1_THREADS) lh[b] = 0;
    __syncthreads();
    int base = blockIdx.x * L1_CHUNK;
    int end  = min(base + L1_CHUNK, NNZTOT);
    // sweep 1: block-local bucket histogram
    for (int i = base + threadIdx.x; i < end; i += L1_THREADS)
        atomicAdd(&lh[edge_idx(i, a1r, a2r) >> 8], 1);
    __syncthreads();
    // reserve spans: lh[b] becomes this block's rolling global cursor
    for (int b = threadIdx.x; b < NBUCK; b += L1_THREADS) {
        int h = lh[b];
        lh[b] = h ? atomicAdd(&cursor[b], h) : 0;
    }
    __syncthreads();
    // sweep 2: write records
    for (int i = base + threadIdx.x; i < end; i += L1_THREADS) {
        int idx, col;
        float val;
        if (i < 2 * NNZ1) {
            idx = ((i < NNZ1) ? 0 : N1) + a1r[i];
            col = a1c[i];
            val = a1v[i];
        } else {
            int j = i - 2 * NNZ1;
            idx = 2 * N1 + ((j < NNZ2) ? 0 : N2) + a2r[j];
            col = a2c[j];
            val = a2v[j];
        }
        int pos = atomicAdd(&lh[idx >> 8], 1);
        lvl1[pos] = make_int2(((idx & 255) << 17) | col, __float_as_int(val));
    }
}

// ---------------- level-2 sort within bucket (one block per bucket) ----------------
// Block exclusively owns its ~16 KB destination range -> clean full-line writes.
// Also writes rpe[idx+1] = row end offsets.
__global__ __launch_bounds__(256) void lvl2_sort_kernel(
        const int2* __restrict__ lvl1, const int* __restrict__ bucketOff,
        int* __restrict__ binned, int* __restrict__ rpe) {
    __shared__ int cnt[256];
    __shared__ int sc[256];
    int b = blockIdx.x;
    int t = threadIdx.x;
    int s0 = bucketOff[b];
    int e0 = bucketOff[b + 1];
    cnt[t] = 0;
    __syncthreads();
    for (int k = s0 + t; k < e0; k += 256)
        atomicAdd(&cnt[lvl1[k].x >> 17], 1);
    __syncthreads();
    int v = cnt[t];
    sc[t] = v;
    __syncthreads();
    for (int off = 1; off < 256; off <<= 1) {
        int y = (t >= off) ? sc[t - off] : 0;
        __syncthreads();
        sc[t] += y;
        __syncthreads();
    }
    int incl = sc[t];
    int excl = incl - v;
    int idx = (b << 8) + t;
    if (idx < NTOT) rpe[idx + 1] = s0 + incl;
    cnt[t] = excl;   // repurpose as local cursor
    __syncthreads();
    for (int k = s0 + t; k < e0; k += 256) {
        int2 rec = lvl1[k];
        int rl  = rec.x >> 17;
        int col = rec.x & 0x1FFFF;
        unsigned bf15 = f2bf(__int_as_float(rec.y)) & 0x7FFFu;
        int pos = atomicAdd(&cnt[rl], 1);
        binned[s0 + pos] = (int)((bf15 << 17) | (unsigned)col);
    }
}

// ---------------- bf16 embedding conversion ----------------
#define TOT8 ((DIAGNUM + MEDNUM + PRONUM) * (FEATDIM / 8))   // 1,760,000

__global__ __launch_bounds__(256) void convert_emb_kernel(
        const float* __restrict__ dE, const float* __restrict__ mE,
        const float* __restrict__ pE,
        ushort_t* __restrict__ embd, ushort_t* __restrict__ embm,
        ushort_t* __restrict__ embp) {
    int t8 = blockIdx.x * 256 + threadIdx.x;
    if (t8 >= TOT8) return;
    long flat = (long)t8 * 8;
    const float* src;
    ushort_t* dst;
    if (flat < (long)DIAGNUM * FEATDIM) {
        src = dE + flat;                          dst = embd + flat;
    } else if (flat < (long)(DIAGNUM + MEDNUM) * FEATDIM) {
        long o = flat - (long)DIAGNUM * FEATDIM;  src = mE + o; dst = embm + o;
    } else {
        long o = flat - (long)(DIAGNUM + MEDNUM) * FEATDIM;
        src = pE + o;                             dst = embp + o;
    }
    float4 a = *reinterpret_cast<const float4*>(src);
    float4 b = *reinterpret_cast<const float4*>(src + 4);
    int4 w;
    w.x = (int)(f2bf(a.x) | (f2bf(a.y) << 16));
    w.y = (int)(f2bf(a.z) | (f2bf(a.w) << 16));
    w.z = (int)(f2bf(b.x) | (f2bf(b.y) << 16));
    w.w = (int)(f2bf(b.z) | (f2bf(b.w) << 16));
    *reinterpret_cast<int4*>(dst) = w;
}

// ---------------- fused GCN row kernel (quarter-wave bf16 gather, 2x unroll) ----------------
// 16 lanes x ushort8 (16 B) per edge, 8 edges in flight per wave.

__device__ __forceinline__ void fma8(float acc[8], float v, int4 h) {
    acc[0] = fmaf(v, __uint_as_float((unsigned)h.x << 16), acc[0]);
    acc[1] = fmaf(v, __uint_as_float((unsigned)h.x & 0xFFFF0000u), acc[1]);
    acc[2] = fmaf(v, __uint_as_float((unsigned)h.y << 16), acc[2]);
    acc[3] = fmaf(v, __uint_as_float((unsigned)h.y & 0xFFFF0000u), acc[3]);
    acc[4] = fmaf(v, __uint_as_float((unsigned)h.z << 16), acc[4]);
    acc[5] = fmaf(v, __uint_as_float((unsigned)h.z & 0xFFFF0000u), acc[5]);
    acc[6] = fmaf(v, __uint_as_float((unsigned)h.w << 16), acc[6]);
    acc[7] = fmaf(v, __uint_as_float((unsigned)h.w & 0xFFFF0000u), acc[7]);
}

__device__ __forceinline__ const ushort_t* rec_base(unsigned rec, int nlo,
                                                    const ushort_t* __restrict__ xlo,
                                                    const ushort_t* __restrict__ xhi) {
    int col = (int)(rec & 0x1FFFFu);
    return (col < nlo) ? xlo + (size_t)col * FEATDIM
                       : xhi + (size_t)(col - nlo) * FEATDIM;
}

__device__ __forceinline__ void gather8(int s, int e,
                                        const int* __restrict__ binned,
                                        int q, int sub16,
                                        const ushort_t* __restrict__ xlo,
                                        const ushort_t* __restrict__ xhi,
                                        int nlo, float acc[8]) {
    int k = s + q;
    for (; k + 4 < e; k += 8) {
        unsigned r0 = (unsigned)binned[k];
        unsigned r1 = (unsigned)binned[k + 4];
        const ushort_t* b0 = rec_base(r0, nlo, xlo, xhi);
        const ushort_t* b1 = rec_base(r1, nlo, xlo, xhi);
        int4 h0 = reinterpret_cast<const int4*>(b0)[sub16];
        int4 h1 = reinterpret_cast<const int4*>(b1)[sub16];
        fma8(acc, __uint_as_float((r0 >> 17) << 16), h0);
        fma8(acc, __uint_as_float((r1 >> 17) << 16), h1);
    }
    for (; k < e; k += 4) {
        unsigned r0 = (unsigned)binned[k];
        const ushort_t* b0 = rec_base(r0, nlo, xlo, xhi);
        int4 h0 = reinterpret_cast<const int4*>(b0)[sub16];
        fma8(acc, __uint_as_float((r0 >> 17) << 16), h0);
    }
}

// One 64-lane wave per output row of ONE graph.
// graph==0 (graph2): med rows -> out_m = (1-t)*res (pure write)
// graph==1 (graph1): med rows -> out_m += t*res    (after graph2 launch)
__global__ __launch_bounds__(256) void fused_gcn_kernel(
        const int* __restrict__ rpe,
        const int* __restrict__ binned,
        const ushort_t* __restrict__ embd, const ushort_t* __restrict__ embm,
        const ushort_t* __restrict__ embp,
        const float* __restrict__ inter,
        float* __restrict__ out_d, float* __restrict__ out_p,
        float* __restrict__ out_m, int graph) {
    int gtid = blockIdx.x * blockDim.x + threadIdx.x;
    int w     = gtid >> 6;
    int lane  = gtid & 63;
    int q     = lane >> 4;
    int sub16 = lane & 15;

    const ushort_t *xlo, *xhi = embm;
    const int *rpA, *rpB;
    int nlo, nrows;
    if (graph) { xlo = embd; nlo = DIAGNUM; nrows = N1;
                 rpA = rpe + w; rpB = rpe + N1 + w; }
    else       { xlo = embp; nlo = PRONUM;  nrows = N2;
                 rpA = rpe + 2 * N1 + w; rpB = rpe + 2 * N1 + N2 + w; }
    if (w >= nrows) return;

    float aA[8] = {0, 0, 0, 0, 0, 0, 0, 0};
    float aB[8] = {0, 0, 0, 0, 0, 0, 0, 0};
    gather8(rpA[0], rpA[1], binned, q, sub16, xlo, xhi, nlo, aA);
    gather8(rpB[0], rpB[1], binned, q, sub16, xlo, xhi, nlo, aB);

    // reduce the 4 quarters
#pragma unroll
    for (int j = 0; j < 8; j++) {
        aA[j] += __shfl_xor(aA[j], 16);
        aA[j] += __shfl_xor(aA[j], 32);
        aB[j] += __shfl_xor(aB[j], 16);
        aB[j] += __shfl_xor(aB[j], 32);
    }

    if (lane >= 16) return;

    float r[8];
#pragma unroll
    for (int j = 0; j < 8; j++)
        r[j] = 2.f * (fmaxf(aA[j], 0.f) + fmaxf(aB[j], 0.f));

    float4 lo = make_float4(r[0], r[1], r[2], r[3]);
    float4 hi = make_float4(r[4], r[5], r[6], r[7]);

    if (graph) {
        if (w < DIAGNUM) {
            float4* dst = reinterpret_cast<float4*>(out_d + (size_t)w * FEATDIM);
            dst[sub16 * 2]     = lo;
            dst[sub16 * 2 + 1] = hi;
        } else {
            float t = *inter;
            float4* dst = reinterpret_cast<float4*>(
                out_m + (size_t)(w - DIAGNUM) * FEATDIM);
            float4 o0 = dst[sub16 * 2];
            float4 o1 = dst[sub16 * 2 + 1];
            o0.x = fmaf(t, lo.x, o0.x); o0.y = fmaf(t, lo.y, o0.y);
            o0.z = fmaf(t, lo.z, o0.z); o0.w = fmaf(t, lo.w, o0.w);
            o1.x = fmaf(t, hi.x, o1.x); o1.y = fmaf(t, hi.y, o1.y);
            o1.z = fmaf(t, hi.z, o1.z); o1.w = fmaf(t, hi.w, o1.w);
            dst[sub16 * 2]     = o0;
            dst[sub16 * 2 + 1] = o1;
        }
    } else {
        if (w < PRONUM) {
            float4* dst = reinterpret_cast<float4*>(out_p + (size_t)w * FEATDIM);
            dst[sub16 * 2]     = lo;
            dst[sub16 * 2 + 1] = hi;
        } else {
            float sc = 1.0f - *inter;
            lo.x *= sc; lo.y *= sc; lo.z *= sc; lo.w *= sc;
            hi.x *= sc; hi.y *= sc; hi.z *= sc; hi.w *= sc;
            float4* dst = reinterpret_cast<float4*>(
                out_m + (size_t)(w - PRONUM) * FEATDIM);
            dst[sub16 * 2]     = lo;
            dst[sub16 * 2 + 1] = hi;
        }
    }
}

// ---------------- host orchestration ----------------

extern "C" void kernel_launch(void* const* d_in, const int* in_sizes, int n_in,
                              void* d_out, int out_size, void* d_ws, size_t ws_size,
                              hipStream_t stream) {
    const int*   a1r = (const int*)d_in[0];
    const int*   a1c = (const int*)d_in[1];
    const float* a1v = (const float*)d_in[2];
    const int*   a2r = (const int*)d_in[3];
    const int*   a2c = (const int*)d_in[4];
    const float* a2v = (const float*)d_in[5];
    const float* dE  = (const float*)d_in[6];
    const float* mE  = (const float*)d_in[7];
    const float* pE  = (const float*)d_in[8];
    const float* inter = (const float*)d_in[9];

    float* out   = (float*)d_out;
    float* out_m = out;                               // 20000*128
    float* out_d = out + (size_t)MEDNUM * FEATDIM;    // 50000*128
    float* out_p = out_d + (size_t)DIAGNUM * FEATDIM; // 40000*128

    // ws layout (~51 MB). regionB is time-shared: lvl1 records (phase 1) then
    // bf16 embeddings (phase 2) — lvl1 is dead before convert_emb runs.
    char* ws = (char*)d_ws;
    int* binned = (int*)ws;          ws += (size_t)NNZTOT * 4;          // 16.64 MB
    char* regionB = ws;              ws += (size_t)NNZTOT * 8;          // 33.28 MB
    int2*     lvl1 = (int2*)regionB;
    ushort_t* embd = (ushort_t*)regionB;
    ushort_t* embm = embd + (size_t)DIAGNUM * FEATDIM;
    ushort_t* embp = embm + (size_t)MEDNUM * FEATDIM;
    int* rpe       = (int*)ws;       ws += (((size_t)(NTOT + 1) * 4 + 15) & ~15ull);
    int* bucketCnt = (int*)ws;       ws += (size_t)NBUCK * 4;
    int* bucketOff = (int*)ws;       ws += (size_t)(NBUCK + 1) * 4;
    int* cursor    = (int*)ws;       ws += (size_t)NBUCK * 4;

    const int BLK = 256;

    hipMemsetAsync(bucketCnt, 0, (size_t)NBUCK * sizeof(int), stream);
    hipMemsetAsync(rpe, 0, sizeof(int), stream);   // rpe[0] = 0

    count_buckets_kernel<<<512, BLK, 0, stream>>>(a1r, a2r, bucketCnt);
    scan_buckets_kernel<<<1, BLK, 0, stream>>>(bucketCnt, bucketOff, cursor);
    lvl1_scatter_kernel<<<L1_BLOCKS, L1_THREADS, 0, stream>>>(
        a1r, a1c, a1v, a2r, a2c, a2v, cursor, lvl1);
    lvl2_sort_kernel<<<NBUCK, BLK, 0, stream>>>(lvl1, bucketOff, binned, rpe);

    convert_emb_kernel<<<(TOT8 + BLK - 1) / BLK, BLK, 0, stream>>>(
        dE, mE, pE, embd, embm, embp);

    // graph 2 first (writes out_m pure), then graph 1 (accumulates out_m)
    fused_gcn_kernel<<<(N2 + 3) / 4, BLK, 0, stream>>>(
        rpe, binned, embd, embm, embp, inter, out_d, out_p, out_m, 0);
    fused_gcn_kernel<<<(N1 + 3) / 4, BLK, 0, stream>>>(
        rpe, binned, embd, embm, embp, inter, out_d, out_p, out_m, 1);
}

// Round 10
// 255.028 us; speedup vs baseline: 11.0331x; 1.0081x over previous
//
#include <hip/hip_runtime.h>
#include <hip/hip_fp16.h>

#define DIAGNUM 50000
#define MEDNUM  20000
#define PRONUM  40000
#define FEATDIM 128
#define N1 (DIAGNUM + MEDNUM)   // 70000
#define N2 (PRONUM + MEDNUM)    // 60000
#define NNZ1 1120000
#define NNZ2 960000
#define NTOT (2 * N1 + 2 * N2)            // 260000 concatenated rows
#define NNZTOT (2 * NNZ1 + 2 * NNZ2)      // 4160000 concatenated edges
#define NBUCK ((NTOT + 255) >> 8)         // 1016 buckets of 256 rows
#define L1_THREADS 512
#define L1_CHUNK 8192
#define L1_ITERS (L1_CHUNK / L1_THREADS)  // 16
#define L1_BLOCKS ((NNZTOT + L1_CHUNK - 1) / L1_CHUNK)   // 508

typedef unsigned short ushort_t;

// concatenated row index for edge i
__device__ __forceinline__ int edge_idx(int i, const int* __restrict__ a1r,
                                        const int* __restrict__ a2r) {
    if (i < 2 * NNZ1) {
        return ((i < NNZ1) ? 0 : N1) + a1r[i];
    } else {
        int j = i - 2 * NNZ1;
        return 2 * N1 + ((j < NNZ2) ? 0 : N2) + a2r[j];
    }
}

// ---------------- bucket count ----------------
__global__ __launch_bounds__(256) void count_buckets_kernel(
        const int* __restrict__ a1r, const int* __restrict__ a2r,
        int* __restrict__ bucketCnt) {
    __shared__ int lh[NBUCK];
    for (int b = threadIdx.x; b < NBUCK; b += 256) lh[b] = 0;
    __syncthreads();
    int stride = gridDim.x * 256;
    for (int i = blockIdx.x * 256 + threadIdx.x; i < NNZTOT; i += stride)
        atomicAdd(&lh[edge_idx(i, a1r, a2r) >> 8], 1);
    __syncthreads();
    for (int b = threadIdx.x; b < NBUCK; b += 256) {
        int h = lh[b];
        if (h) atomicAdd(&bucketCnt[b], h);
    }
}

// ---------------- exclusive scan of bucket counts (single block) ----------------
__global__ __launch_bounds__(256) void scan_buckets_kernel(
        const int* __restrict__ bucketCnt, int* __restrict__ bucketOff,
        int* __restrict__ cursor) {
    __shared__ int s[256];
    int t = threadIdx.x;
    int vals[4];
    int sum = 0;
#pragma unroll
    for (int k = 0; k < 4; k++) {
        int b = t * 4 + k;
        vals[k] = (b < NBUCK) ? bucketCnt[b] : 0;
        sum += vals[k];
    }
    s[t] = sum;
    __syncthreads();
    for (int off = 1; off < 256; off <<= 1) {
        int y = (t >= off) ? s[t - off] : 0;
        __syncthreads();
        s[t] += y;
        __syncthreads();
    }
    int run = s[t] - sum;
#pragma unroll
    for (int k = 0; k < 4; k++) {
        int b = t * 4 + k;
        if (b < NBUCK) {
            bucketOff[b] = run;
            cursor[b] = run;
            run += vals[k];
        }
    }
    if (t == 255) bucketOff[NBUCK] = run;   // == NNZTOT
}

// ---------------- level-1 scatter into coarse buckets ----------------
// 512 threads x 8192-edge chunks; row indices cached in registers across
// sweeps (row array read once).
// record: .x = (row_local << 17) | col   (row_local 8b, col 17b), .y = val bits
__global__ __launch_bounds__(L1_THREADS) void lvl1_scatter_kernel(
        const int* __restrict__ a1r, const int* __restrict__ a1c,
        const float* __restrict__ a1v,
        const int* __restrict__ a2r, const int* __restrict__ a2c,
        const float* __restrict__ a2v,
        int* __restrict__ cursor, int2* __restrict__ lvl1) {
    __shared__ int lh[NBUCK];
    for (int b = threadIdx.x; b < NBUCK; b += L1_THREADS) lh[b] = 0;
    __syncthreads();
    int base = blockIdx.x * L1_CHUNK;
    int end  = min(base + L1_CHUNK, NNZTOT);
    int idxv[L1_ITERS];
    // sweep 1: block-local bucket histogram (cache idx)
    {
        int it = 0;
        for (int i = base + threadIdx.x; i < end; i += L1_THREADS, it++) {
            int idx = edge_idx(i, a1r, a2r);
            idxv[it] = idx;
            atomicAdd(&lh[idx >> 8], 1);
        }
    }
    __syncthreads();
    // reserve spans: lh[b] becomes this block's rolling global cursor
    for (int b = threadIdx.x; b < NBUCK; b += L1_THREADS) {
        int h = lh[b];
        lh[b] = h ? atomicAdd(&cursor[b], h) : 0;
    }
    __syncthreads();
    // sweep 2: write records (col/val only; idx from registers)
    {
        int it = 0;
        for (int i = base + threadIdx.x; i < end; i += L1_THREADS, it++) {
            int col;
            float val;
            if (i < 2 * NNZ1) {
                col = a1c[i];
                val = a1v[i];
            } else {
                int j = i - 2 * NNZ1;
                col = a2c[j];
                val = a2v[j];
            }
            int idx = idxv[it];
            int pos = atomicAdd(&lh[idx >> 8], 1);
            lvl1[pos] = make_int2(((idx & 255) << 17) | col, __float_as_int(val));
        }
    }
}

// ---------------- level-2 sort within bucket (one block per bucket) ----------------
// Block exclusively owns its ~16 KB destination range -> clean full-line writes.
// Final record: 4 B = (fp16(val) << 17) | col  (val in [0,1): sign=0, 15 bits).
// Also writes rpe[idx+1] = row end offsets.
__global__ __launch_bounds__(256) void lvl2_sort_kernel(
        const int2* __restrict__ lvl1, const int* __restrict__ bucketOff,
        int* __restrict__ binned, int* __restrict__ rpe) {
    __shared__ int cnt[256];
    __shared__ int sc[256];
    int b = blockIdx.x;
    int t = threadIdx.x;
    int s0 = bucketOff[b];
    int e0 = bucketOff[b + 1];
    cnt[t] = 0;
    __syncthreads();
    for (int k = s0 + t; k < e0; k += 256)
        atomicAdd(&cnt[lvl1[k].x >> 17], 1);
    __syncthreads();
    int v = cnt[t];
    sc[t] = v;
    __syncthreads();
    for (int off = 1; off < 256; off <<= 1) {
        int y = (t >= off) ? sc[t - off] : 0;
        __syncthreads();
        sc[t] += y;
        __syncthreads();
    }
    int incl = sc[t];
    int excl = incl - v;
    int idx = (b << 8) + t;
    if (idx < NTOT) rpe[idx + 1] = s0 + incl;
    cnt[t] = excl;   // repurpose as local cursor
    __syncthreads();
    for (int k = s0 + t; k < e0; k += 256) {
        int2 rec = lvl1[k];
        int rl  = rec.x >> 17;
        int col = rec.x & 0x1FFFF;
        unsigned hv = __half_as_ushort(__float2half(__int_as_float(rec.y)));
        int pos = atomicAdd(&cnt[rl], 1);
        binned[s0 + pos] = (int)((hv << 17) | (unsigned)col);
    }
}

// ---------------- fp16 embedding conversion (unified per-graph layouts) ----------------
// emb1 = [dE; mE] (N1 x 128), emb2 = [pE; mE] (N2 x 128); med rows duplicated.
#define TOT8 ((DIAGNUM + MEDNUM + PRONUM) * (FEATDIM / 8))   // 1,760,000

__device__ __forceinline__ ushort_t f2h(float x) {
    return __half_as_ushort(__float2half(x));
}

__global__ __launch_bounds__(256) void convert_emb_kernel(
        const float* __restrict__ dE, const float* __restrict__ mE,
        const float* __restrict__ pE,
        ushort_t* __restrict__ emb1, ushort_t* __restrict__ emb2) {
    int t8 = blockIdx.x * 256 + threadIdx.x;
    if (t8 >= TOT8) return;
    long flat = (long)t8 * 8;
    const float* src;
    ushort_t* dst;
    ushort_t* dst2 = nullptr;
    if (flat < (long)DIAGNUM * FEATDIM) {
        src = dE + flat;
        dst = emb1 + flat;
    } else if (flat < (long)(DIAGNUM + MEDNUM) * FEATDIM) {
        long o = flat - (long)DIAGNUM * FEATDIM;
        src = mE + o;
        dst  = emb1 + (long)DIAGNUM * FEATDIM + o;
        dst2 = emb2 + (long)PRONUM * FEATDIM + o;
    } else {
        long o = flat - (long)(DIAGNUM + MEDNUM) * FEATDIM;
        src = pE + o;
        dst = emb2 + o;
    }
    float4 a = *reinterpret_cast<const float4*>(src);
    float4 b = *reinterpret_cast<const float4*>(src + 4);
    int4 w;
    w.x = (int)((unsigned)f2h(a.x) | ((unsigned)f2h(a.y) << 16));
    w.y = (int)((unsigned)f2h(a.z) | ((unsigned)f2h(a.w) << 16));
    w.z = (int)((unsigned)f2h(b.x) | ((unsigned)f2h(b.y) << 16));
    w.w = (int)((unsigned)f2h(b.z) | ((unsigned)f2h(b.w) << 16));
    *reinterpret_cast<int4*>(dst) = w;
    if (dst2) *reinterpret_cast<int4*>(dst2) = w;
}

// ---------------- fused GCN row kernel (quarter-wave fp16 gather, 2x unroll) ----------------
// 16 lanes x 16 B (8 fp16) per edge, 8 edges in flight per wave.
// No base select: unified embedding, addr = emb + (col << 7).

__device__ __forceinline__ void fma8(float acc[8], float v, int4 h) {
    union U { int4 i; __half2 h2[4]; } u;
    u.i = h;
#pragma unroll
    for (int j = 0; j < 4; j++) {
        float2 f = __half22float2(u.h2[j]);
        acc[2 * j]     = fmaf(v, f.x, acc[2 * j]);
        acc[2 * j + 1] = fmaf(v, f.y, acc[2 * j + 1]);
    }
}

__device__ __forceinline__ float rec_val(unsigned rec) {
    return __half2float(__ushort_as_half((unsigned short)(rec >> 17)));
}

__device__ __forceinline__ void gather8(int s, int e,
                                        const int* __restrict__ binned,
                                        int q, int sub16,
                                        const ushort_t* __restrict__ emb,
                                        float acc[8]) {
    int k = s + q;
    for (; k + 4 < e; k += 8) {
        unsigned r0 = (unsigned)binned[k];
        unsigned r1 = (unsigned)binned[k + 4];
        const int4* b0 = reinterpret_cast<const int4*>(emb + ((size_t)(r0 & 0x1FFFFu) << 7));
        const int4* b1 = reinterpret_cast<const int4*>(emb + ((size_t)(r1 & 0x1FFFFu) << 7));
        int4 h0 = b0[sub16];
        int4 h1 = b1[sub16];
        fma8(acc, rec_val(r0), h0);
        fma8(acc, rec_val(r1), h1);
    }
    for (; k < e; k += 4) {
        unsigned r0 = (unsigned)binned[k];
        const int4* b0 = reinterpret_cast<const int4*>(emb + ((size_t)(r0 & 0x1FFFFu) << 7));
        int4 h0 = b0[sub16];
        fma8(acc, rec_val(r0), h0);
    }
}

// One 64-lane wave per output row of ONE graph.
// graph==0 (graph2): med rows -> out_m = (1-t)*res (pure write)
// graph==1 (graph1): med rows -> out_m += t*res    (after graph2 launch)
__global__ __launch_bounds__(256) void fused_gcn_kernel(
        const int* __restrict__ rpe,
        const int* __restrict__ binned,
        const ushort_t* __restrict__ emb,   // unified layout for this graph
        const float* __restrict__ inter,
        float* __restrict__ out_d, float* __restrict__ out_p,
        float* __restrict__ out_m, int graph) {
    int gtid = blockIdx.x * blockDim.x + threadIdx.x;
    int w     = gtid >> 6;
    int lane  = gtid & 63;
    int q     = lane >> 4;
    int sub16 = lane & 15;

    const int *rpA, *rpB;
    int nrows;
    if (graph) { nrows = N1; rpA = rpe + w; rpB = rpe + N1 + w; }
    else       { nrows = N2; rpA = rpe + 2 * N1 + w; rpB = rpe + 2 * N1 + N2 + w; }
    if (w >= nrows) return;

    float aA[8] = {0, 0, 0, 0, 0, 0, 0, 0};
    float aB[8] = {0, 0, 0, 0, 0, 0, 0, 0};
    gather8(rpA[0], rpA[1], binned, q, sub16, emb, aA);
    gather8(rpB[0], rpB[1], binned, q, sub16, emb, aB);

    // reduce the 4 quarters
#pragma unroll
    for (int j = 0; j < 8; j++) {
        aA[j] += __shfl_xor(aA[j], 16);
        aA[j] += __shfl_xor(aA[j], 32);
        aB[j] += __shfl_xor(aB[j], 16);
        aB[j] += __shfl_xor(aB[j], 32);
    }

    if (lane >= 16) return;

    float r[8];
#pragma unroll
    for (int j = 0; j < 8; j++)
        r[j] = 2.f * (fmaxf(aA[j], 0.f) + fmaxf(aB[j], 0.f));

    float4 lo = make_float4(r[0], r[1], r[2], r[3]);
    float4 hi = make_float4(r[4], r[5], r[6], r[7]);

    if (graph) {
        if (w < DIAGNUM) {
            float4* dst = reinterpret_cast<float4*>(out_d + (size_t)w * FEATDIM);
            dst[sub16 * 2]     = lo;
            dst[sub16 * 2 + 1] = hi;
        } else {
            float t = *inter;
            float4* dst = reinterpret_cast<float4*>(
                out_m + (size_t)(w - DIAGNUM) * FEATDIM);
            float4 o0 = dst[sub16 * 2];
            float4 o1 = dst[sub16 * 2 + 1];
            o0.x = fmaf(t, lo.x, o0.x); o0.y = fmaf(t, lo.y, o0.y);
            o0.z = fmaf(t, lo.z, o0.z); o0.w = fmaf(t, lo.w, o0.w);
            o1.x = fmaf(t, hi.x, o1.x); o1.y = fmaf(t, hi.y, o1.y);
            o1.z = fmaf(t, hi.z, o1.z); o1.w = fmaf(t, hi.w, o1.w);
            dst[sub16 * 2]     = o0;
            dst[sub16 * 2 + 1] = o1;
        }
    } else {
        if (w < PRONUM) {
            float4* dst = reinterpret_cast<float4*>(out_p + (size_t)w * FEATDIM);
            dst[sub16 * 2]     = lo;
            dst[sub16 * 2 + 1] = hi;
        } else {
            float sc = 1.0f - *inter;
            lo.x *= sc; lo.y *= sc; lo.z *= sc; lo.w *= sc;
            hi.x *= sc; hi.y *= sc; hi.z *= sc; hi.w *= sc;
            float4* dst = reinterpret_cast<float4*>(
                out_m + (size_t)(w - PRONUM) * FEATDIM);
            dst[sub16 * 2]     = lo;
            dst[sub16 * 2 + 1] = hi;
        }
    }
}

// ---------------- host orchestration ----------------

extern "C" void kernel_launch(void* const* d_in, const int* in_sizes, int n_in,
                              void* d_out, int out_size, void* d_ws, size_t ws_size,
                              hipStream_t stream) {
    const int*   a1r = (const int*)d_in[0];
    const int*   a1c = (const int*)d_in[1];
    const float* a1v = (const float*)d_in[2];
    const int*   a2r = (const int*)d_in[3];
    const int*   a2c = (const int*)d_in[4];
    const float* a2v = (const float*)d_in[5];
    const float* dE  = (const float*)d_in[6];
    const float* mE  = (const float*)d_in[7];
    const float* pE  = (const float*)d_in[8];
    const float* inter = (const float*)d_in[9];

    float* out   = (float*)d_out;
    float* out_m = out;                               // 20000*128
    float* out_d = out + (size_t)MEDNUM * FEATDIM;    // 50000*128
    float* out_p = out_d + (size_t)DIAGNUM * FEATDIM; // 40000*128

    // ws layout (~51 MB). regionB is time-shared: lvl1 records (sort phase),
    // then fp16 unified embeddings (emb1 17.92 MB + emb2 15.36 MB = 33.28 MB)
    // — lvl1 is dead after lvl2_sort, before convert_emb runs.
    char* ws = (char*)d_ws;
    int* binned = (int*)ws;          ws += (size_t)NNZTOT * 4;          // 16.64 MB
    char* regionB = ws;              ws += (size_t)NNZTOT * 8;          // 33.28 MB
    int2*     lvl1 = (int2*)regionB;
    ushort_t* emb1 = (ushort_t*)regionB;                    // N1*128 fp16
    ushort_t* emb2 = emb1 + (size_t)N1 * FEATDIM;           // N2*128 fp16
    int* rpe       = (int*)ws;       ws += (((size_t)(NTOT + 1) * 4 + 15) & ~15ull);
    int* bucketCnt = (int*)ws;       ws += (size_t)NBUCK * 4;
    int* bucketOff = (int*)ws;       ws += (size_t)(NBUCK + 1) * 4;
    int* cursor    = (int*)ws;       ws += (size_t)NBUCK * 4;

    const int BLK = 256;

    hipMemsetAsync(bucketCnt, 0, (size_t)NBUCK * sizeof(int), stream);
    hipMemsetAsync(rpe, 0, sizeof(int), stream);   // rpe[0] = 0

    count_buckets_kernel<<<512, BLK, 0, stream>>>(a1r, a2r, bucketCnt);
    scan_buckets_kernel<<<1, BLK, 0, stream>>>(bucketCnt, bucketOff, cursor);
    lvl1_scatter_kernel<<<L1_BLOCKS, L1_THREADS, 0, stream>>>(
        a1r, a1c, a1v, a2r, a2c, a2v, cursor, lvl1);
    lvl2_sort_kernel<<<NBUCK, BLK, 0, stream>>>(lvl1, bucketOff, binned, rpe);

    // lvl1 dead now; regionB becomes fp16 embeddings
    convert_emb_kernel<<<(TOT8 + BLK - 1) / BLK, BLK, 0, stream>>>(
        dE, mE, pE, emb1, emb2);

    // graph 2 first (writes out_m pure), then graph 1 (accumulates out_m)
    fused_gcn_kernel<<<(N2 + 3) / 4, BLK, 0, stream>>>(
        rpe, binned, emb2, inter, out_d, out_p, out_m, 0);
    fused_gcn_kernel<<<(N1 + 3) / 4, BLK, 0, stream>>>(
        rpe, binned, emb1, inter, out_d, out_p, out_m, 1);
}